// Round 4
// baseline (376079.810 us; speedup 1.0000x reference)
//
#include <hip/hip_runtime.h>

#define NB 32
#define TENC 300
#define TDEC 500
#define NMEL 80
#define ENCD 512
#define PRE 256
#define ADIM 128

// ---------------- workspace layout (float offsets) ----------------
#define OFF_DECINS 0ull                         // 500*32*256 = 4,096,000
#define OFF_H1M    4096000ull                   // prenet scratch; aliases loop buffers below
#define OFF_GPA    4096000ull                   // 4*32*4096 = 524,288
#define OFF_GPD    (OFF_GPA + 524288ull)        // 524,288
#define OFF_E      (OFF_GPD + 524288ull)        // 9,600
#define OFF_PM     8192000ull                   // 32*300*128 = 1,228,800
#define OFF_STATE  (OFF_PM + 1228800ull)        // = 9,420,800
#define OFF_AH0    (OFF_STATE + 0ull)
#define OFF_AH1    (OFF_STATE + 32768ull)
#define OFF_AC0    (OFF_STATE + 65536ull)
#define OFF_AC1    (OFF_STATE + 98304ull)
#define OFF_DH0    (OFF_STATE + 131072ull)
#define OFF_DH1    (OFF_STATE + 163840ull)
#define OFF_DC     (OFF_STATE + 196608ull)
#define OFF_CTX    (OFF_STATE + 229376ull)      // 16,384
#define OFF_AW     (OFF_STATE + 245760ull)      // 9,600
#define OFF_AWC    (OFF_STATE + 255360ull)      // 9,600
#define OFF_BAR    (OFF_STATE + 264960ull)      // 64 (grid barrier: count, gen)
#define STATE_N    265024ull
#define OFF_QWT    (OFF_STATE + STATE_N)        // 131,072
#define OFF_PROJWT (OFF_QWT + 131072ull)        // 122,880
#define OFF_MWT    (OFF_PROJWT + 122880ull)     // 65,536
#define OFF_W1T    (OFF_MWT + 65536ull)         // 20,480
#define OFF_W2T    (OFF_W1T + 20480ull)         // 65,536

// ---------------- threefry2x32 (matches JAX bit-exactly) ----------------
__host__ __device__ __forceinline__ unsigned rotl32(unsigned v, int r){ return (v<<r)|(v>>(32-r)); }

__host__ __device__ __forceinline__ void tf2x32(unsigned k0, unsigned k1, unsigned c0, unsigned c1,
                                                unsigned& y0, unsigned& y1){
  unsigned ks2 = k0 ^ k1 ^ 0x1BD11BDAu;
  unsigned x0 = c0 + k0, x1 = c1 + k1;
#define TFR(r) x0 += x1; x1 = rotl32(x1, r); x1 ^= x0;
  TFR(13) TFR(15) TFR(26) TFR(6)
  x0 += k1;  x1 += ks2 + 1u;
  TFR(17) TFR(29) TFR(16) TFR(24)
  x0 += ks2; x1 += k0 + 2u;
  TFR(13) TFR(15) TFR(26) TFR(6)
  x0 += k0;  x1 += k1 + 3u;
  TFR(17) TFR(29) TFR(16) TFR(24)
  x0 += k1;  x1 += ks2 + 4u;
  TFR(13) TFR(15) TFR(26) TFR(6)
  x0 += ks2; x1 += k0 + 5u;
#undef TFR
  y0 = x0; y1 = x1;
}

// Partitionable threefry random_bits: bits(i) = y0^y1 of threefry2x32(key,(0,i))
__device__ __forceinline__ float mask_scale(unsigned k0, unsigned k1, unsigned idx){
  unsigned y0, y1;
  tf2x32(k0, k1, 0u, idx, y0, y1);
  unsigned bits = y0 ^ y1;
  float u = __uint_as_float((bits >> 9) | 0x3f800000u) - 1.0f;
  return (u < 0.9f) ? (1.0f/0.9f) : 0.0f;
}

// ---------------- manual grid barrier (device-scope atomics, all 256 blocks co-resident) ----------------
__device__ __forceinline__ void gbar(unsigned* bar, int nb){
  __syncthreads();
  __threadfence();   // release: make this block's writes visible device-wide (cross-XCD)
  if (threadIdx.x == 0){
    unsigned gen = __hip_atomic_load(bar + 1, __ATOMIC_RELAXED, __HIP_MEMORY_SCOPE_AGENT);
    unsigned prev = __hip_atomic_fetch_add(bar, 1u, __ATOMIC_ACQ_REL, __HIP_MEMORY_SCOPE_AGENT);
    if (prev == (unsigned)(nb - 1)){
      __hip_atomic_store(bar, 0u, __ATOMIC_RELAXED, __HIP_MEMORY_SCOPE_AGENT);
      __hip_atomic_fetch_add(bar + 1, 1u, __ATOMIC_RELEASE, __HIP_MEMORY_SCOPE_AGENT);
    } else {
      while (__hip_atomic_load(bar + 1, __ATOMIC_RELAXED, __HIP_MEMORY_SCOPE_AGENT) == gen)
        __builtin_amdgcn_s_sleep(1);
    }
  }
  __syncthreads();
  __threadfence();   // acquire: invalidate stale cachelines before reading others' data
}

// ---------------- setup: zero states + weight transposes ----------------
__global__ __launch_bounds__(256) void k_setup(float* __restrict__ ws,
    const float* __restrict__ qW, const float* __restrict__ projW, const float* __restrict__ mW,
    const float* __restrict__ w1, const float* __restrict__ w2){
  long i = (long)blockIdx.x*256 + threadIdx.x;
  long stride = (long)gridDim.x*256;
  float* st = ws + OFF_STATE;
  for (long x = i; x < (long)STATE_N; x += stride) st[x] = 0.f;
  float* qWT = ws + OFF_QWT;     // [1024][128]
  for (long x = i; x < 1024*128; x += stride){ int u = x>>7, d = x&127; qWT[x] = qW[(size_t)d*1024+u]; }
  float* pWT = ws + OFF_PROJWT;  // [1536][80]
  for (long x = i; x < 1536*80; x += stride){ int k = x/80, m = x%80; pWT[x] = projW[(size_t)m*1536+k]; }
  float* mWT = ws + OFF_MWT;     // [512][128]
  for (long x = i; x < 512*128; x += stride){ int k = x>>7, d = x&127; mWT[x] = mW[(size_t)d*512+k]; }
  float* w1T = ws + OFF_W1T;     // [80][256]
  for (long x = i; x < 80*256; x += stride){ int m = x>>8, u = x&255; w1T[x] = w1[(size_t)u*80+m]; }
  float* w2T = ws + OFF_W2T;     // [256][256]
  for (long x = i; x < 256*256; x += stride){ int k = x>>8, u = x&255; w2T[x] = w2[(size_t)u*256+k]; }
}

// ---------------- prenet ----------------
__global__ __launch_bounds__(256) void k_prenet1(const float* __restrict__ di,
    const float* __restrict__ W1T, float* __restrict__ h1m, unsigned k10, unsigned k11){
  __shared__ float xs[NMEL];
  int bid = blockIdx.x;           // t*32 + b
  int t = bid >> 5, b = bid & 31;
  int tid = threadIdx.x;
  if (tid < NMEL) xs[tid] = (t == 0) ? 0.f : di[(size_t)b*40000 + (size_t)tid*500 + (t-1)];
  __syncthreads();
  float acc = 0.f;
  for (int m = 0; m < NMEL; ++m) acc += xs[m] * W1T[m*256 + tid];
  acc = fmaxf(acc, 0.f);
  unsigned idx = (unsigned)bid*256u + (unsigned)tid;
  h1m[(size_t)bid*256 + tid] = acc * mask_scale(k10, k11, idx);
}

__global__ __launch_bounds__(256) void k_prenet2(const float* __restrict__ h1m,
    const float* __restrict__ W2T, float* __restrict__ dec_ins, unsigned k20, unsigned k21){
  __shared__ float hs[PRE];
  int bid = blockIdx.x;
  int tid = threadIdx.x;
  hs[tid] = h1m[(size_t)bid*256 + tid];
  __syncthreads();
  float acc = 0.f;
  for (int k = 0; k < PRE; ++k) acc += hs[k] * W2T[k*256 + tid];
  acc = fmaxf(acc, 0.f);
  unsigned idx = (unsigned)bid*256u + (unsigned)tid;
  dec_ins[(size_t)bid*256 + tid] = acc * mask_scale(k20, k21, idx);
}

// ---------------- processed memory ----------------
__global__ __launch_bounds__(128) void k_procmem(const float* __restrict__ mem,
    const float* __restrict__ mWT, float* __restrict__ pm){
  __shared__ float ms[ENCD];
  int bid = blockIdx.x;  // b*300 + j
  int tid = threadIdx.x;
  const float* src = mem + (size_t)bid*ENCD;
  for (int i = tid; i < ENCD; i += 128) ms[i] = src[i];
  __syncthreads();
  float acc = 0.f;
  for (int k = 0; k < ENCD; ++k) acc += ms[k] * mWT[k*128 + tid];
  pm[(size_t)bid*128 + tid] = acc;
}

// ---------------- GEMM task ----------------
// task in [0,256): rt = task&63, ks = task>>6.  partials gp[(ks*32+b)*4096+row]
__device__ __forceinline__ void gemm_task(int task, const float* __restrict__ W1, const float* __restrict__ W2,
    const float* __restrict__ s0, int l0, const float* __restrict__ s1, const float* __restrict__ hseg,
    int Ktot, float* __restrict__ gp, int tid){
  __shared__ float Xs[32][32];
  __shared__ float Ws[64][36];
  int rt = task & 63, ks = task >> 6;
  int rp = tid & 31, bq = tid >> 5;
  int xw = l0 + 512;
  int kr = Ktot >> 2;
  int kbeg = ks*kr, kend = kbeg + kr;
  int row0 = rt*64;
  float acc[2][4] = {};
  for (int kc = kbeg; kc < kend; kc += 32){
#pragma unroll
    for (int i = 0; i < 4; ++i){
      int flat = tid + i*256;
      int b = flat >> 5, kk = flat & 31;
      int k = kc + kk;
      float v;
      if (k < l0) v = s0[(size_t)b*l0 + k];
      else if (k < xw) v = s1[(b<<9) + (k - l0)];
      else v = hseg[(b<<10) + (k - xw)];
      Xs[b][kk] = v;
    }
#pragma unroll
    for (int i = 0; i < 8; ++i){
      int flat = tid + i*256;
      int r = flat >> 5, kk = flat & 31;
      int k = kc + kk;
      int row = row0 + r;
      Ws[r][kk] = (k < xw) ? W1[(size_t)row*xw + k] : W2[((size_t)row<<10) + (k - xw)];
    }
    __syncthreads();
#pragma unroll
    for (int kk = 0; kk < 32; kk += 4){
      float4 w0 = *(const float4*)&Ws[2*rp][kk];
      float4 w1 = *(const float4*)&Ws[2*rp+1][kk];
#pragma unroll
      for (int j = 0; j < 4; ++j){
        float4 xv = *(const float4*)&Xs[bq + 8*j][kk];
        acc[0][j] += w0.x*xv.x; acc[0][j] += w0.y*xv.y; acc[0][j] += w0.z*xv.z; acc[0][j] += w0.w*xv.w;
        acc[1][j] += w1.x*xv.x; acc[1][j] += w1.y*xv.y; acc[1][j] += w1.z*xv.z; acc[1][j] += w1.w*xv.w;
      }
    }
    __syncthreads();
  }
#pragma unroll
  for (int rr = 0; rr < 2; ++rr)
#pragma unroll
    for (int j = 0; j < 4; ++j){
      int b = bq + 8*j;
      gp[((size_t)(ks*32 + b))*4096 + row0 + 2*rp + rr] = acc[rr][j];
    }
}

// ---------------- LSTM epilogue body (4 K-split partials) ----------------
__device__ __forceinline__ void lstm_body(const float* __restrict__ gp, const float* __restrict__ bih,
    const float* __restrict__ bhh, const float* __restrict__ cin, float* __restrict__ cout,
    float* __restrict__ hout, float* __restrict__ sH, int b, int tid, bool wr){
  int u0 = tid*4;
  float gs[4][4];
#pragma unroll
  for (int g = 0; g < 4; ++g){
    float4 s  = *(const float4*)&bih[g*1024 + u0];
    float4 s2 = *(const float4*)&bhh[g*1024 + u0];
    float a0 = s.x + s2.x, a1 = s.y + s2.y, a2 = s.z + s2.z, a3 = s.w + s2.w;
    const float* base = gp + (size_t)b*4096 + g*1024 + u0;
#pragma unroll
    for (int ks = 0; ks < 4; ++ks){
      float4 p = *(const float4*)(base + (size_t)ks*131072);
      a0 += p.x; a1 += p.y; a2 += p.z; a3 += p.w;
    }
    gs[g][0]=a0; gs[g][1]=a1; gs[g][2]=a2; gs[g][3]=a3;
  }
  float4 c4 = *(const float4*)&cin[b*1024 + u0];
  float cold[4] = {c4.x, c4.y, c4.z, c4.w};
  float cn[4], hn[4];
#pragma unroll
  for (int e = 0; e < 4; ++e){
    float ii = 1.f/(1.f + expf(-gs[0][e]));
    float ff = 1.f/(1.f + expf(-gs[1][e]));
    float gg = tanhf(gs[2][e]);
    float oo = 1.f/(1.f + expf(-gs[3][e]));
    float c = ff*cold[e] + ii*gg;
    cn[e] = c; hn[e] = oo*tanhf(c);
  }
  if (wr){
    *(float4*)&cout[b*1024 + u0] = make_float4(cn[0],cn[1],cn[2],cn[3]);
    *(float4*)&hout[b*1024 + u0] = make_float4(hn[0],hn[1],hn[2],hn[3]);
  }
  sH[u0]=hn[0]; sH[u0+1]=hn[1]; sH[u0+2]=hn[2]; sH[u0+3]=hn[3];
}

// ---------------- energy tile (16 j's) ----------------
__device__ __forceinline__ void energy_tile(int b, int tile,
    const float* __restrict__ aw, const float* __restrict__ awc,
    const float* __restrict__ lcW, const float* __restrict__ ldW, const float* __restrict__ vw,
    const float* __restrict__ sPq, const float* __restrict__ pm, float* __restrict__ e_ws, int tid){
  __shared__ float sIn[2][46];
  __shared__ float cfs[16][33];
  __shared__ float ep[16][17];
  int j0 = tile*16;
  if (tid < 46){ int j = j0 - 15 + tid; sIn[0][tid] = (j >= 0 && j < 300) ? aw[b*300 + j] : 0.f; }
  else if (tid < 92){ int i = tid - 46; int j = j0 - 15 + i; sIn[1][i] = (j >= 0 && j < 300) ? awc[b*300 + j] : 0.f; }
  __syncthreads();
  { // conv
    int fg = tid & 15, jl = tid >> 4;
    int f0 = 2*fg;
    float c0 = 0.f, c1 = 0.f;
#pragma unroll
    for (int c = 0; c < 2; ++c)
#pragma unroll
      for (int k = 0; k < 31; ++k){
        float a = sIn[c][jl + k];
        c0 += a * lcW[f0*62 + c*31 + k];
        c1 += a * lcW[(f0+1)*62 + c*31 + k];
      }
    cfs[jl][f0] = c0; cfs[jl][f0+1] = c1;
  }
  __syncthreads();
  { // dense + tanh + v
    int dg = tid & 15, jl = tid >> 4;
    int j = j0 + jl;
    float s = 0.f;
    if (j < 300){
      const float* pmrow = pm + ((size_t)(b*300 + j))*128 + dg*8;
#pragma unroll
      for (int dd = 0; dd < 8; ++dd){
        int d = dg*8 + dd;
        float acc = sPq[d] + pmrow[dd];
#pragma unroll
        for (int f = 0; f < 32; ++f) acc += cfs[jl][f] * ldW[d*32 + f];
        s += vw[d] * tanhf(acc);
      }
    }
    ep[jl][dg] = s;
  }
  __syncthreads();
  if (tid < 16){
    int j = j0 + tid;
    if (j < 300){
      float s = 0.f;
#pragma unroll
      for (int dg = 0; dg < 16; ++dg) s += ep[tid][dg];
      e_ws[b*300 + j] = s;
    }
  }
  __syncthreads();
}

// ---------------- P2: redundant att-LSTM + pq + energy slice ----------------
__device__ __forceinline__ void p2_phase(int b, int jt, const float* __restrict__ gpA,
    const float* __restrict__ bih, const float* __restrict__ bhh,
    const float* __restrict__ acin, float* __restrict__ acout, float* __restrict__ ahout,
    const float* __restrict__ qWT, const float* __restrict__ aw, const float* __restrict__ awc,
    const float* __restrict__ lcW, const float* __restrict__ ldW, const float* __restrict__ vw,
    const float* __restrict__ pm, float* __restrict__ e_ws, int tid){
  __shared__ float sAh[1024];
  __shared__ float pqs[256];
  __shared__ float sPq[128];
  lstm_body(gpA, bih, bhh, acin, acout, ahout, sAh, b, tid, jt == 0);
  __syncthreads();
  int d = tid & 127, half = tid >> 7;
  const float* qt = qWT + (size_t)(half*512)*128 + d;
  float acc = 0.f;
  for (int u = 0; u < 512; ++u) acc += sAh[half*512 + u] * qt[(size_t)u*128];
  pqs[half*128 + d] = acc;
  __syncthreads();
  if (tid < 128) sPq[tid] = pqs[tid] + pqs[128 + tid];
  __syncthreads();
  for (int tile = jt; tile < 19; tile += 8)
    energy_tile(b, tile, aw, awc, lcW, ldW, vw, sPq, pm, e_ws, tid);
}

// ---------------- P3: softmax + ctx + awc + alignment ----------------
__device__ __forceinline__ void soft_phase(int b, const float* __restrict__ e_ws, const int* __restrict__ lens,
    const float* __restrict__ mem, float* __restrict__ aw, float* __restrict__ awc, float* __restrict__ ctx,
    float* __restrict__ out, int t, int tid){
  __shared__ float se[300];
  __shared__ float sa[300];
  __shared__ float red[256];
  int len = lens[b];
  for (int j = tid; j < 300; j += 256) se[j] = e_ws[b*300 + j];
  __syncthreads();
  float m = -1e30f;
  for (int j = tid; j < len; j += 256) m = fmaxf(m, se[j]);
  red[tid] = m; __syncthreads();
  for (int s = 128; s > 0; s >>= 1){ if (tid < s) red[tid] = fmaxf(red[tid], red[tid + s]); __syncthreads(); }
  float mx = red[0]; __syncthreads();
  float ss = 0.f;
  for (int j = tid; j < len; j += 256) ss += expf(se[j] - mx);
  red[tid] = ss; __syncthreads();
  for (int s = 128; s > 0; s >>= 1){ if (tid < s) red[tid] += red[tid + s]; __syncthreads(); }
  float inv = 1.f/red[0];
  float* al = out + 1296000 + (size_t)b*150000 + (size_t)t*300;
  for (int j = tid; j < 300; j += 256){
    float v = (j < len) ? expf(se[j] - mx)*inv : 0.f;
    sa[j] = v;
    aw[b*300 + j] = v;
    awc[b*300 + j] += v;
    al[j] = v;
  }
  __syncthreads();
  const float* mb = mem + (size_t)b*300*512;
  for (int d = tid; d < 512; d += 256){
    float acc = 0.f;
    for (int j = 0; j < len; ++j) acc += sa[j]*mb[(size_t)j*512 + d];
    ctx[b*512 + d] = acc;
  }
}

// ---------------- P5: dec-LSTM epilogue + mel/gate ----------------
__device__ __forceinline__ void dec_epilogue(int b, const float* __restrict__ gpD,
    const float* __restrict__ bih, const float* __restrict__ bhh,
    float* __restrict__ dc, float* __restrict__ dh_out, const float* __restrict__ ctx,
    const float* __restrict__ pWT, const float* __restrict__ projb,
    const float* __restrict__ gateW, const float* __restrict__ gateb,
    float* __restrict__ out, int t, int tid){
  __shared__ float sDh[1024];
  __shared__ float sCtx[512];
  __shared__ float red[256];
  __shared__ float melp[3][80];
  lstm_body(gpD, bih, bhh, dc, dc, dh_out, sDh, b, tid, true);
  for (int i = tid; i < 512; i += 256) sCtx[i] = ctx[b*512 + i];
  __syncthreads();
  if (tid < 240){
    int m = tid % 80, seg = tid / 80;
    float mp = 0.f;
    for (int k = seg*512; k < seg*512 + 512; ++k){
      float x = (k < 1024) ? sDh[k] : sCtx[k - 1024];
      mp += x * pWT[(size_t)k*80 + m];
    }
    melp[seg][m] = mp;
  }
  float g = 0.f;
  for (int k = tid; k < 1536; k += 256){
    float x = (k < 1024) ? sDh[k] : sCtx[k - 1024];
    g += x * gateW[k];
  }
  red[tid] = g; __syncthreads();
  for (int s = 128; s > 0; s >>= 1){ if (tid < s) red[tid] += red[tid + s]; __syncthreads(); }
  if (tid == 0) out[1280000 + (size_t)b*500 + t] = red[0] + gateb[0];
  if (tid < 80){
    float mel = melp[0][tid] + melp[1][tid] + melp[2][tid] + projb[tid];
    out[(size_t)b*40000 + (size_t)tid*500 + t] = mel;
  }
  __syncthreads();
}

// ---------------- persistent loop (regular launch + manual grid barrier) ----------------
struct DecParams {
  const float *memory;
  const int   *lens;
  const float *attWih, *attWhh, *attBih, *attBhh;
  const float *decWih, *decWhh, *decBih, *decBhh;
  const float *lcW, *ldW, *vw, *projb, *gateW, *gateb;
  float *ws, *out;
};

__global__ void __launch_bounds__(256, 1) k_loop(DecParams p){
  int wg = blockIdx.x, tid = threadIdx.x;
  float* ws = p.ws;
  float* decins = ws + OFF_DECINS;
  float* gpA = ws + OFF_GPA;
  float* gpD = ws + OFF_GPD;
  float* e_ws = ws + OFF_E;
  float* pm = ws + OFF_PM;
  float* AH[2] = { ws + OFF_AH0, ws + OFF_AH1 };
  float* AC[2] = { ws + OFF_AC0, ws + OFF_AC1 };
  float* DH[2] = { ws + OFF_DH0, ws + OFF_DH1 };
  float* DC = ws + OFF_DC;
  float* ctx = ws + OFF_CTX;
  float* aw = ws + OFF_AW;
  float* awc = ws + OFF_AWC;
  float* qWT = ws + OFF_QWT;
  float* pWT = ws + OFF_PROJWT;
  unsigned* bar = (unsigned*)(ws + OFF_BAR);

  // P1 for t=0 (ctx, AH0 zeroed by k_setup)
  gemm_task(wg, p.attWih, p.attWhh, decins, PRE, ctx, AH[0], 1792, gpA, tid);
  gbar(bar, 256);

  for (int t = 0; t < TDEC; ++t){
    // P2: att-LSTM epilogue (redundant per (b,jt)) + pq + energy slices  [all 256 WGs]
    {
      int b = wg >> 3, jt = wg & 7;
      p2_phase(b, jt, gpA, p.attBih, p.attBhh, AC[t & 1], AC[(t + 1) & 1], AH[(t + 1) & 1],
               qWT, aw, awc, p.lcW, p.ldW, p.vw, pm, e_ws, tid);
    }
    gbar(bar, 256);
    // P3: softmax + ctx + awc + alignment  [32 WGs]
    if (wg < 32) soft_phase(wg, e_ws, p.lens, p.memory, aw, awc, ctx, p.out, t, tid);
    gbar(bar, 256);
    // P4: dec GEMM  [all 256 WGs]
    gemm_task(wg, p.decWih, p.decWhh, AH[(t + 1) & 1], 1024, ctx, DH[t & 1], 2560, gpD, tid);
    gbar(bar, 256);
    // P5 (dec epilogue, 32 WGs)  ||  P1 for t+1 (att GEMM, 256 tasks)
    if (wg < 32){
      dec_epilogue(wg, gpD, p.decBih, p.decBhh, DC, DH[(t + 1) & 1], ctx,
                   pWT, p.projb, p.gateW, p.gateb, p.out, t, tid);
      if (t + 1 < TDEC)
        gemm_task(224 + wg, p.attWih, p.attWhh, decins + (size_t)(t + 1)*NB*PRE, PRE,
                  ctx, AH[(t + 1) & 1], 1792, gpA, tid);
    } else {
      if (t + 1 < TDEC)
        gemm_task(wg - 32, p.attWih, p.attWhh, decins + (size_t)(t + 1)*NB*PRE, PRE,
                  ctx, AH[(t + 1) & 1], 1792, gpA, tid);
    }
    gbar(bar, 256);
  }
}

// ---------------- host ----------------
extern "C" void kernel_launch(void* const* d_in, const int* in_sizes, int n_in,
                              void* d_out, int out_size, void* d_ws, size_t ws_size,
                              hipStream_t stream) {
  const float* memory   = (const float*)d_in[0];
  const float* dec_in   = (const float*)d_in[1];
  const int*   lens     = (const int*)  d_in[2];
  const float* pre_W1   = (const float*)d_in[3];
  const float* pre_W2   = (const float*)d_in[4];
  const float* att_Wih  = (const float*)d_in[5];
  const float* att_Whh  = (const float*)d_in[6];
  const float* att_bih  = (const float*)d_in[7];
  const float* att_bhh  = (const float*)d_in[8];
  const float* q_W      = (const float*)d_in[9];
  const float* m_W      = (const float*)d_in[10];
  const float* v_w      = (const float*)d_in[11];
  const float* lc_W     = (const float*)d_in[12];
  const float* ld_W     = (const float*)d_in[13];
  const float* dec_Wih  = (const float*)d_in[14];
  const float* dec_Whh  = (const float*)d_in[15];
  const float* dec_bih  = (const float*)d_in[16];
  const float* dec_bhh  = (const float*)d_in[17];
  const float* proj_W   = (const float*)d_in[18];
  const float* proj_b   = (const float*)d_in[19];
  const float* gate_W   = (const float*)d_in[20];
  const float* gate_b   = (const float*)d_in[21];
  float* out = (float*)d_out;
  float* ws  = (float*)d_ws;

  // Partitionable (foldlike) split of jax.random.key(1)
  unsigned k10, k11, k20, k21;
  tf2x32(0u, 1u, 0u, 0u, k10, k11);
  tf2x32(0u, 1u, 0u, 1u, k20, k21);

  k_setup<<<1024, 256, 0, stream>>>(ws, q_W, proj_W, m_W, pre_W1, pre_W2);
  k_prenet1<<<TDEC*NB, 256, 0, stream>>>(dec_in, ws + OFF_W1T, ws + OFF_H1M, k10, k11);
  k_prenet2<<<TDEC*NB, 256, 0, stream>>>(ws + OFF_H1M, ws + OFF_W2T, ws + OFF_DECINS, k20, k21);
  k_procmem<<<NB*TENC, 128, 0, stream>>>(memory, ws + OFF_MWT, ws + OFF_PM);

  DecParams hp;
  hp.memory = memory; hp.lens = lens;
  hp.attWih = att_Wih; hp.attWhh = att_Whh; hp.attBih = att_bih; hp.attBhh = att_bhh;
  hp.decWih = dec_Wih; hp.decWhh = dec_Whh; hp.decBih = dec_bih; hp.decBhh = dec_bhh;
  hp.lcW = lc_W; hp.ldW = ld_W; hp.vw = v_w; hp.projb = proj_b; hp.gateW = gate_W; hp.gateb = gate_b;
  hp.ws = ws; hp.out = out;
  k_loop<<<256, 256, 0, stream>>>(hp);
}

// Round 5
// 281765.674 us; speedup vs baseline: 1.3347x; 1.3347x over previous
//
#include <hip/hip_runtime.h>

#define NB 32
#define TENC 300
#define TDEC 500
#define NMEL 80
#define ENCD 512
#define PRE 256
#define ADIM 128

// ---------------- workspace layout (float offsets) ----------------
#define OFF_DECINS 0ull                         // 500*32*256 = 4,096,000
#define OFF_H1M    4096000ull                   // prenet scratch; aliases loop buffers below
#define OFF_GPA    4096000ull                   // 4*32*4096 = 524,288
#define OFF_GPD    (OFF_GPA + 524288ull)        // 524,288
#define OFF_E      (OFF_GPD + 524288ull)        // 9,600
#define OFF_PM     8192000ull                   // 32*300*128 = 1,228,800
#define OFF_STATE  (OFF_PM + 1228800ull)        // = 9,420,800
#define OFF_AH0    (OFF_STATE + 0ull)
#define OFF_AH1    (OFF_STATE + 32768ull)
#define OFF_AC0    (OFF_STATE + 65536ull)
#define OFF_AC1    (OFF_STATE + 98304ull)
#define OFF_DH0    (OFF_STATE + 131072ull)
#define OFF_DH1    (OFF_STATE + 163840ull)
#define OFF_DC     (OFF_STATE + 196608ull)
#define OFF_CTX    (OFF_STATE + 229376ull)      // 16,384
#define OFF_AW     (OFF_STATE + 245760ull)      // 9,600
#define OFF_AWC    (OFF_STATE + 255360ull)      // 9,600
#define OFF_SLOTS  (OFF_STATE + 264960ull)      // 256 slots * 16 u32 + gen
#define STATE_N    269072ull
#define OFF_QWT    (OFF_STATE + STATE_N)        // 131,072
#define OFF_PROJWT (OFF_QWT + 131072ull)        // 122,880
#define OFF_MWT    (OFF_PROJWT + 122880ull)     // 65,536
#define OFF_W1T    (OFF_MWT + 65536ull)         // 20,480
#define OFF_W2T    (OFF_W1T + 20480ull)         // 65,536

// ---------------- device-coherent (agent-scope, fence-free) access helpers ----------------
__device__ __forceinline__ float gload(const float* p){
  return __hip_atomic_load(p, __ATOMIC_RELAXED, __HIP_MEMORY_SCOPE_AGENT);
}
__device__ __forceinline__ void gstore(float* p, float v){
  __hip_atomic_store(p, v, __ATOMIC_RELAXED, __HIP_MEMORY_SCOPE_AGENT);
}
__device__ __forceinline__ float2 gload2(const float* p){
  unsigned long long u = __hip_atomic_load((const unsigned long long*)p, __ATOMIC_RELAXED, __HIP_MEMORY_SCOPE_AGENT);
  float2 r; r.x = __uint_as_float((unsigned)u); r.y = __uint_as_float((unsigned)(u >> 32)); return r;
}
__device__ __forceinline__ void gstore2(float* p, float a, float b){
  unsigned long long u = (unsigned long long)__float_as_uint(a) | ((unsigned long long)__float_as_uint(b) << 32);
  __hip_atomic_store((unsigned long long*)p, u, __ATOMIC_RELAXED, __HIP_MEMORY_SCOPE_AGENT);
}

// ---------------- contention-free grid barrier (slot flags + generation) ----------------
// Requires all 256 blocks co-resident. __syncthreads() drains each wave's vmcnt before
// s_barrier (compiler-guaranteed), so the slot store publishes all prior sc1 data stores.
__device__ __forceinline__ void gbar(unsigned* slots, unsigned* gen, unsigned epoch){
  int wg = blockIdx.x, tid = threadIdx.x;
  __syncthreads();
  if (wg == 0){
    if (tid != 0){
      while (__hip_atomic_load(&slots[tid*16], __ATOMIC_RELAXED, __HIP_MEMORY_SCOPE_AGENT) < epoch)
        __builtin_amdgcn_s_sleep(4);
    }
    __syncthreads();
    if (tid == 0)
      __hip_atomic_store(gen, epoch, __ATOMIC_RELAXED, __HIP_MEMORY_SCOPE_AGENT);
  } else {
    if (tid == 0){
      __hip_atomic_store(&slots[wg*16], epoch, __ATOMIC_RELAXED, __HIP_MEMORY_SCOPE_AGENT);
      while (__hip_atomic_load(gen, __ATOMIC_RELAXED, __HIP_MEMORY_SCOPE_AGENT) < epoch)
        __builtin_amdgcn_s_sleep(4);
    }
    __syncthreads();
  }
}

// ---------------- threefry2x32 (matches JAX bit-exactly) ----------------
__host__ __device__ __forceinline__ unsigned rotl32(unsigned v, int r){ return (v<<r)|(v>>(32-r)); }

__host__ __device__ __forceinline__ void tf2x32(unsigned k0, unsigned k1, unsigned c0, unsigned c1,
                                                unsigned& y0, unsigned& y1){
  unsigned ks2 = k0 ^ k1 ^ 0x1BD11BDAu;
  unsigned x0 = c0 + k0, x1 = c1 + k1;
#define TFR(r) x0 += x1; x1 = rotl32(x1, r); x1 ^= x0;
  TFR(13) TFR(15) TFR(26) TFR(6)
  x0 += k1;  x1 += ks2 + 1u;
  TFR(17) TFR(29) TFR(16) TFR(24)
  x0 += ks2; x1 += k0 + 2u;
  TFR(13) TFR(15) TFR(26) TFR(6)
  x0 += k0;  x1 += k1 + 3u;
  TFR(17) TFR(29) TFR(16) TFR(24)
  x0 += k1;  x1 += ks2 + 4u;
  TFR(13) TFR(15) TFR(26) TFR(6)
  x0 += ks2; x1 += k0 + 5u;
#undef TFR
  y0 = x0; y1 = x1;
}

// Partitionable threefry random_bits: bits(i) = y0^y1 of threefry2x32(key,(0,i))
__device__ __forceinline__ float mask_scale(unsigned k0, unsigned k1, unsigned idx){
  unsigned y0, y1;
  tf2x32(k0, k1, 0u, idx, y0, y1);
  unsigned bits = y0 ^ y1;
  float u = __uint_as_float((bits >> 9) | 0x3f800000u) - 1.0f;
  return (u < 0.9f) ? (1.0f/0.9f) : 0.0f;
}

// ---------------- setup: zero states + weight transposes ----------------
__global__ __launch_bounds__(256) void k_setup(float* __restrict__ ws,
    const float* __restrict__ qW, const float* __restrict__ projW, const float* __restrict__ mW,
    const float* __restrict__ w1, const float* __restrict__ w2){
  long i = (long)blockIdx.x*256 + threadIdx.x;
  long stride = (long)gridDim.x*256;
  float* st = ws + OFF_STATE;
  for (long x = i; x < (long)STATE_N; x += stride) st[x] = 0.f;
  float* qWT = ws + OFF_QWT;     // [1024][128]
  for (long x = i; x < 1024*128; x += stride){ int u = x>>7, d = x&127; qWT[x] = qW[(size_t)d*1024+u]; }
  float* pWT = ws + OFF_PROJWT;  // [1536][80]
  for (long x = i; x < 1536*80; x += stride){ int k = x/80, m = x%80; pWT[x] = projW[(size_t)m*1536+k]; }
  float* mWT = ws + OFF_MWT;     // [512][128]
  for (long x = i; x < 512*128; x += stride){ int k = x>>7, d = x&127; mWT[x] = mW[(size_t)d*512+k]; }
  float* w1T = ws + OFF_W1T;     // [80][256]
  for (long x = i; x < 80*256; x += stride){ int m = x>>8, u = x&255; w1T[x] = w1[(size_t)u*80+m]; }
  float* w2T = ws + OFF_W2T;     // [256][256]
  for (long x = i; x < 256*256; x += stride){ int k = x>>8, u = x&255; w2T[x] = w2[(size_t)u*256+k]; }
}

// ---------------- prenet ----------------
__global__ __launch_bounds__(256) void k_prenet1(const float* __restrict__ di,
    const float* __restrict__ W1T, float* __restrict__ h1m, unsigned k10, unsigned k11){
  __shared__ float xs[NMEL];
  int bid = blockIdx.x;           // t*32 + b
  int t = bid >> 5, b = bid & 31;
  int tid = threadIdx.x;
  if (tid < NMEL) xs[tid] = (t == 0) ? 0.f : di[(size_t)b*40000 + (size_t)tid*500 + (t-1)];
  __syncthreads();
  float acc = 0.f;
  for (int m = 0; m < NMEL; ++m) acc += xs[m] * W1T[m*256 + tid];
  acc = fmaxf(acc, 0.f);
  unsigned idx = (unsigned)bid*256u + (unsigned)tid;
  h1m[(size_t)bid*256 + tid] = acc * mask_scale(k10, k11, idx);
}

__global__ __launch_bounds__(256) void k_prenet2(const float* __restrict__ h1m,
    const float* __restrict__ W2T, float* __restrict__ dec_ins, unsigned k20, unsigned k21){
  __shared__ float hs[PRE];
  int bid = blockIdx.x;
  int tid = threadIdx.x;
  hs[tid] = h1m[(size_t)bid*256 + tid];
  __syncthreads();
  float acc = 0.f;
  for (int k = 0; k < PRE; ++k) acc += hs[k] * W2T[k*256 + tid];
  acc = fmaxf(acc, 0.f);
  unsigned idx = (unsigned)bid*256u + (unsigned)tid;
  dec_ins[(size_t)bid*256 + tid] = acc * mask_scale(k20, k21, idx);
}

// ---------------- processed memory ----------------
__global__ __launch_bounds__(128) void k_procmem(const float* __restrict__ mem,
    const float* __restrict__ mWT, float* __restrict__ pm){
  __shared__ float ms[ENCD];
  int bid = blockIdx.x;  // b*300 + j
  int tid = threadIdx.x;
  const float* src = mem + (size_t)bid*ENCD;
  for (int i = tid; i < ENCD; i += 128) ms[i] = src[i];
  __syncthreads();
  float acc = 0.f;
  for (int k = 0; k < ENCD; ++k) acc += ms[k] * mWT[k*128 + tid];
  pm[(size_t)bid*128 + tid] = acc;
}

// ---------------- GEMM task ----------------
// task in [0,256): rt = task&63, ks = task>>6.  partials gp[(ks*32+b)*4096+row]
// X rows (coherent, sc1) are staged into an LDS slab in K-halves of <=224 cols;
// W reads are normal cached loads (read-only -> L2 stays hot across all steps).
__device__ __forceinline__ void gemm_task(int task, const float* __restrict__ W1, const float* __restrict__ W2,
    const float* __restrict__ s0, int l0, const float* __restrict__ s1, const float* __restrict__ hseg,
    int Ktot, float* __restrict__ gp, int tid){
  __shared__ float Xslab[32*224];
  __shared__ float Ws[64][36];
  int rt = task & 63, ks = task >> 6;
  int rp = tid & 31, bq = tid >> 5;
  int xw = l0 + 512;
  int kr = Ktot >> 2;
  int kbeg = ks*kr;
  int row0 = rt*64;
  float acc[2][4] = {};
  for (int k0 = kbeg; k0 < kbeg + kr; k0 += 224){
    int cnt = min(224, kbeg + kr - k0);   // 224 or 192, always multiple of 32
    int half = cnt >> 1;
    for (int i = tid; i < 32*half; i += 256){
      int b = i / half, kk = (i - b*half)*2;
      int k = k0 + kk;
      const float* src;
      if (k < l0) src = s0 + (size_t)b*l0 + k;
      else if (k < xw) src = s1 + (b<<9) + (k - l0);
      else src = hseg + (b<<10) + (k - xw);
      float2 v = gload2(src);
      Xslab[b*224 + kk] = v.x; Xslab[b*224 + kk + 1] = v.y;
    }
    __syncthreads();
    for (int kc = 0; kc < cnt; kc += 32){
#pragma unroll
      for (int i = 0; i < 8; ++i){
        int flat = tid + i*256;
        int r = flat >> 5, kk = flat & 31;
        int k = k0 + kc + kk;
        int row = row0 + r;
        Ws[r][kk] = (k < xw) ? W1[(size_t)row*xw + k] : W2[((size_t)row<<10) + (k - xw)];
      }
      __syncthreads();
#pragma unroll
      for (int kk = 0; kk < 32; kk += 4){
        float4 w0 = *(const float4*)&Ws[2*rp][kk];
        float4 w1 = *(const float4*)&Ws[2*rp+1][kk];
#pragma unroll
        for (int j = 0; j < 4; ++j){
          float4 xv = *(const float4*)&Xslab[(bq + 8*j)*224 + kc + kk];
          acc[0][j] += w0.x*xv.x; acc[0][j] += w0.y*xv.y; acc[0][j] += w0.z*xv.z; acc[0][j] += w0.w*xv.w;
          acc[1][j] += w1.x*xv.x; acc[1][j] += w1.y*xv.y; acc[1][j] += w1.z*xv.z; acc[1][j] += w1.w*xv.w;
        }
      }
      __syncthreads();
    }
  }
#pragma unroll
  for (int j = 0; j < 4; ++j){
    int b = bq + 8*j;
    gstore2(&gp[((size_t)(ks*32 + b))*4096 + row0 + 2*rp], acc[0][j], acc[1][j]);
  }
}

// ---------------- LSTM epilogue body (4 K-split partials, coherent reads) ----------------
__device__ __forceinline__ void lstm_body(const float* __restrict__ gp, const float* __restrict__ bih,
    const float* __restrict__ bhh, const float* __restrict__ cin, float* __restrict__ cout,
    float* __restrict__ hout, float* __restrict__ sH, int b, int tid, bool wr){
  int u0 = tid*4;
  float gs[4][4];
#pragma unroll
  for (int g = 0; g < 4; ++g){
    float4 s  = *(const float4*)&bih[g*1024 + u0];
    float4 s2 = *(const float4*)&bhh[g*1024 + u0];
    float a0 = s.x + s2.x, a1 = s.y + s2.y, a2 = s.z + s2.z, a3 = s.w + s2.w;
    const float* base = gp + (size_t)b*4096 + g*1024 + u0;
#pragma unroll
    for (int ks = 0; ks < 4; ++ks){
      float2 p0 = gload2(base + (size_t)ks*131072);
      float2 p1 = gload2(base + (size_t)ks*131072 + 2);
      a0 += p0.x; a1 += p0.y; a2 += p1.x; a3 += p1.y;
    }
    gs[g][0]=a0; gs[g][1]=a1; gs[g][2]=a2; gs[g][3]=a3;
  }
  float2 c01 = gload2(&cin[b*1024 + u0]);
  float2 c23 = gload2(&cin[b*1024 + u0 + 2]);
  float cold[4] = {c01.x, c01.y, c23.x, c23.y};
  float cn[4], hn[4];
#pragma unroll
  for (int e = 0; e < 4; ++e){
    float ii = 1.f/(1.f + expf(-gs[0][e]));
    float ff = 1.f/(1.f + expf(-gs[1][e]));
    float gg = tanhf(gs[2][e]);
    float oo = 1.f/(1.f + expf(-gs[3][e]));
    float c = ff*cold[e] + ii*gg;
    cn[e] = c; hn[e] = oo*tanhf(c);
  }
  if (wr){
    gstore2(&cout[b*1024 + u0], cn[0], cn[1]);
    gstore2(&cout[b*1024 + u0 + 2], cn[2], cn[3]);
    gstore2(&hout[b*1024 + u0], hn[0], hn[1]);
    gstore2(&hout[b*1024 + u0 + 2], hn[2], hn[3]);
  }
  sH[u0]=hn[0]; sH[u0+1]=hn[1]; sH[u0+2]=hn[2]; sH[u0+3]=hn[3];
}

// ---------------- energy tile (16 j's) ----------------
__device__ __forceinline__ void energy_tile(int b, int tile,
    const float* __restrict__ aw, const float* __restrict__ awc,
    const float* __restrict__ lcW, const float* __restrict__ ldW, const float* __restrict__ vw,
    const float* __restrict__ sPq, const float* __restrict__ pm, float* __restrict__ e_ws, int tid){
  __shared__ float sIn[2][46];
  __shared__ float cfs[16][33];
  __shared__ float ep[16][17];
  int j0 = tile*16;
  if (tid < 46){ int j = j0 - 15 + tid; sIn[0][tid] = (j >= 0 && j < 300) ? gload(&aw[b*300 + j]) : 0.f; }
  else if (tid < 92){ int i = tid - 46; int j = j0 - 15 + i; sIn[1][i] = (j >= 0 && j < 300) ? gload(&awc[b*300 + j]) : 0.f; }
  __syncthreads();
  { // conv
    int fg = tid & 15, jl = tid >> 4;
    int f0 = 2*fg;
    float c0 = 0.f, c1 = 0.f;
#pragma unroll
    for (int c = 0; c < 2; ++c)
#pragma unroll
      for (int k = 0; k < 31; ++k){
        float a = sIn[c][jl + k];
        c0 += a * lcW[f0*62 + c*31 + k];
        c1 += a * lcW[(f0+1)*62 + c*31 + k];
      }
    cfs[jl][f0] = c0; cfs[jl][f0+1] = c1;
  }
  __syncthreads();
  { // dense + tanh + v
    int dg = tid & 15, jl = tid >> 4;
    int j = j0 + jl;
    float s = 0.f;
    if (j < 300){
      const float* pmrow = pm + ((size_t)(b*300 + j))*128 + dg*8;
#pragma unroll
      for (int dd = 0; dd < 8; ++dd){
        int d = dg*8 + dd;
        float acc = sPq[d] + pmrow[dd];
#pragma unroll
        for (int f = 0; f < 32; ++f) acc += cfs[jl][f] * ldW[d*32 + f];
        s += vw[d] * tanhf(acc);
      }
    }
    ep[jl][dg] = s;
  }
  __syncthreads();
  if (tid < 16){
    int j = j0 + tid;
    if (j < 300){
      float s = 0.f;
#pragma unroll
      for (int dg = 0; dg < 16; ++dg) s += ep[tid][dg];
      gstore(&e_ws[b*300 + j], s);
    }
  }
  __syncthreads();
}

// ---------------- P2: redundant att-LSTM + pq + energy slice ----------------
__device__ __forceinline__ void p2_phase(int b, int jt, const float* __restrict__ gpA,
    const float* __restrict__ bih, const float* __restrict__ bhh,
    const float* __restrict__ acin, float* __restrict__ acout, float* __restrict__ ahout,
    const float* __restrict__ qWT, const float* __restrict__ aw, const float* __restrict__ awc,
    const float* __restrict__ lcW, const float* __restrict__ ldW, const float* __restrict__ vw,
    const float* __restrict__ pm, float* __restrict__ e_ws, int tid){
  __shared__ float sAh[1024];
  __shared__ float pqs[256];
  __shared__ float sPq[128];
  lstm_body(gpA, bih, bhh, acin, acout, ahout, sAh, b, tid, jt == 0);
  __syncthreads();
  int d = tid & 127, half = tid >> 7;
  const float* qt = qWT + (size_t)(half*512)*128 + d;
  float acc = 0.f;
  for (int u = 0; u < 512; ++u) acc += sAh[half*512 + u] * qt[(size_t)u*128];
  pqs[half*128 + d] = acc;
  __syncthreads();
  if (tid < 128) sPq[tid] = pqs[tid] + pqs[128 + tid];
  __syncthreads();
  for (int tile = jt; tile < 19; tile += 8)
    energy_tile(b, tile, aw, awc, lcW, ldW, vw, sPq, pm, e_ws, tid);
}

// ---------------- P3: softmax + ctx + awc + alignment ----------------
__device__ __forceinline__ void soft_phase(int b, const float* __restrict__ e_ws, const int* __restrict__ lens,
    const float* __restrict__ mem, float* __restrict__ aw, float* __restrict__ awc, float* __restrict__ ctx,
    float* __restrict__ out, int t, int tid){
  __shared__ float se[300];
  __shared__ float sa[300];
  __shared__ float red[256];
  int len = lens[b];
  for (int j = tid; j < 300; j += 256) se[j] = gload(&e_ws[b*300 + j]);
  __syncthreads();
  float m = -1e30f;
  for (int j = tid; j < len; j += 256) m = fmaxf(m, se[j]);
  red[tid] = m; __syncthreads();
  for (int s = 128; s > 0; s >>= 1){ if (tid < s) red[tid] = fmaxf(red[tid], red[tid + s]); __syncthreads(); }
  float mx = red[0]; __syncthreads();
  float ss = 0.f;
  for (int j = tid; j < len; j += 256) ss += expf(se[j] - mx);
  red[tid] = ss; __syncthreads();
  for (int s = 128; s > 0; s >>= 1){ if (tid < s) red[tid] += red[tid + s]; __syncthreads(); }
  float inv = 1.f/red[0];
  float* al = out + 1296000 + (size_t)b*150000 + (size_t)t*300;
  for (int j = tid; j < 300; j += 256){
    float v = (j < len) ? expf(se[j] - mx)*inv : 0.f;
    sa[j] = v;
    gstore(&aw[b*300 + j], v);
    gstore(&awc[b*300 + j], gload(&awc[b*300 + j]) + v);
    al[j] = v;
  }
  __syncthreads();
  const float* mb = mem + (size_t)b*300*512;
  for (int d = tid; d < 512; d += 256){
    float acc = 0.f;
    for (int j = 0; j < len; ++j) acc += sa[j]*mb[(size_t)j*512 + d];
    gstore(&ctx[b*512 + d], acc);
  }
}

// ---------------- P5: dec-LSTM epilogue + mel/gate ----------------
__device__ __forceinline__ void dec_epilogue(int b, const float* __restrict__ gpD,
    const float* __restrict__ bih, const float* __restrict__ bhh,
    float* __restrict__ dc, float* __restrict__ dh_out, const float* __restrict__ ctx,
    const float* __restrict__ pWT, const float* __restrict__ projb,
    const float* __restrict__ gateW, const float* __restrict__ gateb,
    float* __restrict__ out, int t, int tid){
  __shared__ float sDh[1024];
  __shared__ float sCtx[512];
  __shared__ float red[256];
  __shared__ float melp[3][80];
  lstm_body(gpD, bih, bhh, dc, dc, dh_out, sDh, b, tid, true);
  for (int i = tid; i < 512; i += 256) sCtx[i] = gload(&ctx[b*512 + i]);
  __syncthreads();
  if (tid < 240){
    int m = tid % 80, seg = tid / 80;
    float mp = 0.f;
    for (int k = seg*512; k < seg*512 + 512; ++k){
      float x = (k < 1024) ? sDh[k] : sCtx[k - 1024];
      mp += x * pWT[(size_t)k*80 + m];
    }
    melp[seg][m] = mp;
  }
  float g = 0.f;
  for (int k = tid; k < 1536; k += 256){
    float x = (k < 1024) ? sDh[k] : sCtx[k - 1024];
    g += x * gateW[k];
  }
  red[tid] = g; __syncthreads();
  for (int s = 128; s > 0; s >>= 1){ if (tid < s) red[tid] += red[tid + s]; __syncthreads(); }
  if (tid == 0) out[1280000 + (size_t)b*500 + t] = red[0] + gateb[0];
  if (tid < 80){
    float mel = melp[0][tid] + melp[1][tid] + melp[2][tid] + projb[tid];
    out[(size_t)b*40000 + (size_t)tid*500 + t] = mel;
  }
  __syncthreads();
}

// ---------------- persistent loop ----------------
struct DecParams {
  const float *memory;
  const int   *lens;
  const float *attWih, *attWhh, *attBih, *attBhh;
  const float *decWih, *decWhh, *decBih, *decBhh;
  const float *lcW, *ldW, *vw, *projb, *gateW, *gateb;
  float *ws, *out;
};

__global__ void __launch_bounds__(256, 1) k_loop(DecParams p){
  int wg = blockIdx.x, tid = threadIdx.x;
  float* ws = p.ws;
  float* decins = ws + OFF_DECINS;
  float* gpA = ws + OFF_GPA;
  float* gpD = ws + OFF_GPD;
  float* e_ws = ws + OFF_E;
  float* pm = ws + OFF_PM;
  float* AH[2] = { ws + OFF_AH0, ws + OFF_AH1 };
  float* AC[2] = { ws + OFF_AC0, ws + OFF_AC1 };
  float* DH[2] = { ws + OFF_DH0, ws + OFF_DH1 };
  float* DC = ws + OFF_DC;
  float* ctx = ws + OFF_CTX;
  float* aw = ws + OFF_AW;
  float* awc = ws + OFF_AWC;
  float* qWT = ws + OFF_QWT;
  float* pWT = ws + OFF_PROJWT;
  unsigned* slots = (unsigned*)(ws + OFF_SLOTS);
  unsigned* gen = slots + 4096;
  unsigned ep = 0;

  // P1 for t=0 (ctx, AH0 zeroed by k_setup)
  gemm_task(wg, p.attWih, p.attWhh, decins, PRE, ctx, AH[0], 1792, gpA, tid);
  gbar(slots, gen, ++ep);

  for (int t = 0; t < TDEC; ++t){
    // P2: att-LSTM epilogue (redundant per (b,jt)) + pq + energy slices  [all 256 WGs]
    {
      int b = wg >> 3, jt = wg & 7;
      p2_phase(b, jt, gpA, p.attBih, p.attBhh, AC[t & 1], AC[(t + 1) & 1], AH[(t + 1) & 1],
               qWT, aw, awc, p.lcW, p.ldW, p.vw, pm, e_ws, tid);
    }
    gbar(slots, gen, ++ep);
    // P3: softmax + ctx + awc + alignment  [32 WGs]
    if (wg < 32) soft_phase(wg, e_ws, p.lens, p.memory, aw, awc, ctx, p.out, t, tid);
    gbar(slots, gen, ++ep);
    // P4: dec GEMM  [all 256 WGs]
    gemm_task(wg, p.decWih, p.decWhh, AH[(t + 1) & 1], 1024, ctx, DH[t & 1], 2560, gpD, tid);
    gbar(slots, gen, ++ep);
    // P5 (dec epilogue, 32 WGs)  ||  P1 for t+1 (att GEMM, 256 tasks)
    if (wg < 32){
      dec_epilogue(wg, gpD, p.decBih, p.decBhh, DC, DH[(t + 1) & 1], ctx,
                   pWT, p.projb, p.gateW, p.gateb, p.out, t, tid);
      if (t + 1 < TDEC)
        gemm_task(224 + wg, p.attWih, p.attWhh, decins + (size_t)(t + 1)*NB*PRE, PRE,
                  ctx, AH[(t + 1) & 1], 1792, gpA, tid);
    } else {
      if (t + 1 < TDEC)
        gemm_task(wg - 32, p.attWih, p.attWhh, decins + (size_t)(t + 1)*NB*PRE, PRE,
                  ctx, AH[(t + 1) & 1], 1792, gpA, tid);
    }
    gbar(slots, gen, ++ep);
  }
}

// ---------------- host ----------------
extern "C" void kernel_launch(void* const* d_in, const int* in_sizes, int n_in,
                              void* d_out, int out_size, void* d_ws, size_t ws_size,
                              hipStream_t stream) {
  const float* memory   = (const float*)d_in[0];
  const float* dec_in   = (const float*)d_in[1];
  const int*   lens     = (const int*)  d_in[2];
  const float* pre_W1   = (const float*)d_in[3];
  const float* pre_W2   = (const float*)d_in[4];
  const float* att_Wih  = (const float*)d_in[5];
  const float* att_Whh  = (const float*)d_in[6];
  const float* att_bih  = (const float*)d_in[7];
  const float* att_bhh  = (const float*)d_in[8];
  const float* q_W      = (const float*)d_in[9];
  const float* m_W      = (const float*)d_in[10];
  const float* v_w      = (const float*)d_in[11];
  const float* lc_W     = (const float*)d_in[12];
  const float* ld_W     = (const float*)d_in[13];
  const float* dec_Wih  = (const float*)d_in[14];
  const float* dec_Whh  = (const float*)d_in[15];
  const float* dec_bih  = (const float*)d_in[16];
  const float* dec_bhh  = (const float*)d_in[17];
  const float* proj_W   = (const float*)d_in[18];
  const float* proj_b   = (const float*)d_in[19];
  const float* gate_W   = (const float*)d_in[20];
  const float* gate_b   = (const float*)d_in[21];
  float* out = (float*)d_out;
  float* ws  = (float*)d_ws;

  // Partitionable (foldlike) split of jax.random.key(1)
  unsigned k10, k11, k20, k21;
  tf2x32(0u, 1u, 0u, 0u, k10, k11);
  tf2x32(0u, 1u, 0u, 1u, k20, k21);

  k_setup<<<1024, 256, 0, stream>>>(ws, q_W, proj_W, m_W, pre_W1, pre_W2);
  k_prenet1<<<TDEC*NB, 256, 0, stream>>>(dec_in, ws + OFF_W1T, ws + OFF_H1M, k10, k11);
  k_prenet2<<<TDEC*NB, 256, 0, stream>>>(ws + OFF_H1M, ws + OFF_W2T, ws + OFF_DECINS, k20, k21);
  k_procmem<<<NB*TENC, 128, 0, stream>>>(memory, ws + OFF_MWT, ws + OFF_PM);

  DecParams hp;
  hp.memory = memory; hp.lens = lens;
  hp.attWih = att_Wih; hp.attWhh = att_Whh; hp.attBih = att_bih; hp.attBhh = att_bhh;
  hp.decWih = dec_Wih; hp.decWhh = dec_Whh; hp.decBih = dec_bih; hp.decBhh = dec_bhh;
  hp.lcW = lc_W; hp.ldW = ld_W; hp.vw = v_w; hp.projb = proj_b; hp.gateW = gate_W; hp.gateb = gate_b;
  hp.ws = ws; hp.out = out;
  k_loop<<<256, 256, 0, stream>>>(hp);
}

// Round 6
// 190643.286 us; speedup vs baseline: 1.9727x; 1.4780x over previous
//
#include <hip/hip_runtime.h>

#define NB 32
#define TENC 300
#define TDEC 500
#define NMEL 80
#define ENCD 512
#define PRE 256
#define ADIM 128

// ---------------- workspace layout (float offsets) ----------------
#define OFF_DECINS 0ull                         // 500*32*256 = 4,096,000
#define OFF_H1M    4096000ull                   // prenet scratch (pre-loop only)
#define OFF_PM     8192000ull                   // 32*300*128 = 1,228,800
#define OFF_STATE  (OFF_PM + 1228800ull)        // = 9,420,800
#define OFF_AH0    (OFF_STATE + 0ull)
#define OFF_AH1    (OFF_STATE + 32768ull)
#define OFF_AC     (OFF_STATE + 65536ull)
#define OFF_DH0    (OFF_STATE + 98304ull)
#define OFF_DH1    (OFF_STATE + 131072ull)
#define OFF_DC     (OFF_STATE + 163840ull)
#define OFF_CTX    (OFF_STATE + 196608ull)      // 16,384
#define OFF_AW     (OFF_STATE + 212992ull)      // 9,600
#define OFF_AWC    (OFF_STATE + 222592ull)      // 9,600
#define OFF_E      (OFF_STATE + 232192ull)      // 9,600
#define OFF_SLOTS  (OFF_STATE + 241792ull)      // 4,104 u32 (256 slots*16 + gen)
#define STATE_N    245896ull
#define OFF_QWT    (OFF_STATE + STATE_N)        // 131,072
#define OFF_PROJWT (OFF_QWT + 131072ull)        // 122,880
#define OFF_MWT    (OFF_PROJWT + 122880ull)     // 65,536
#define OFF_W1T    (OFF_MWT + 65536ull)         // 20,480
#define OFF_W2T    (OFF_W1T + 20480ull)         // 65,536

// ---------------- device-coherent (agent-scope, fence-free) helpers ----------------
__device__ __forceinline__ float gload(const float* p){
  return __hip_atomic_load(p, __ATOMIC_RELAXED, __HIP_MEMORY_SCOPE_AGENT);
}
__device__ __forceinline__ void gstore(float* p, float v){
  __hip_atomic_store(p, v, __ATOMIC_RELAXED, __HIP_MEMORY_SCOPE_AGENT);
}
__device__ __forceinline__ float2 gload2(const float* p){
  unsigned long long u = __hip_atomic_load((const unsigned long long*)p, __ATOMIC_RELAXED, __HIP_MEMORY_SCOPE_AGENT);
  float2 r; r.x = __uint_as_float((unsigned)u); r.y = __uint_as_float((unsigned)(u >> 32)); return r;
}

// ---------------- contention-free grid barrier ----------------
__device__ __forceinline__ void gbar(unsigned* slots, unsigned* gen, unsigned epoch){
  int wg = blockIdx.x, tid = threadIdx.x;
  __syncthreads();
  if (wg == 0){
    if (tid != 0){
      while (__hip_atomic_load(&slots[tid*16], __ATOMIC_RELAXED, __HIP_MEMORY_SCOPE_AGENT) < epoch)
        __builtin_amdgcn_s_sleep(2);
    }
    __syncthreads();
    if (tid == 0)
      __hip_atomic_store(gen, epoch, __ATOMIC_RELAXED, __HIP_MEMORY_SCOPE_AGENT);
  } else {
    if (tid == 0){
      __hip_atomic_store(&slots[wg*16], epoch, __ATOMIC_RELAXED, __HIP_MEMORY_SCOPE_AGENT);
      while (__hip_atomic_load(gen, __ATOMIC_RELAXED, __HIP_MEMORY_SCOPE_AGENT) < epoch)
        __builtin_amdgcn_s_sleep(2);
    }
    __syncthreads();
  }
}

// ---------------- threefry2x32 (matches JAX bit-exactly) ----------------
__host__ __device__ __forceinline__ unsigned rotl32(unsigned v, int r){ return (v<<r)|(v>>(32-r)); }

__host__ __device__ __forceinline__ void tf2x32(unsigned k0, unsigned k1, unsigned c0, unsigned c1,
                                                unsigned& y0, unsigned& y1){
  unsigned ks2 = k0 ^ k1 ^ 0x1BD11BDAu;
  unsigned x0 = c0 + k0, x1 = c1 + k1;
#define TFR(r) x0 += x1; x1 = rotl32(x1, r); x1 ^= x0;
  TFR(13) TFR(15) TFR(26) TFR(6)
  x0 += k1;  x1 += ks2 + 1u;
  TFR(17) TFR(29) TFR(16) TFR(24)
  x0 += ks2; x1 += k0 + 2u;
  TFR(13) TFR(15) TFR(26) TFR(6)
  x0 += k0;  x1 += k1 + 3u;
  TFR(17) TFR(29) TFR(16) TFR(24)
  x0 += k1;  x1 += ks2 + 4u;
  TFR(13) TFR(15) TFR(26) TFR(6)
  x0 += ks2; x1 += k0 + 5u;
#undef TFR
  y0 = x0; y1 = x1;
}

__device__ __forceinline__ float mask_scale(unsigned k0, unsigned k1, unsigned idx){
  unsigned y0, y1;
  tf2x32(k0, k1, 0u, idx, y0, y1);
  unsigned bits = y0 ^ y1;
  float u = __uint_as_float((bits >> 9) | 0x3f800000u) - 1.0f;
  return (u < 0.9f) ? (1.0f/0.9f) : 0.0f;
}

// ---------------- setup ----------------
__global__ __launch_bounds__(256) void k_setup(float* __restrict__ ws,
    const float* __restrict__ qW, const float* __restrict__ projW, const float* __restrict__ mW,
    const float* __restrict__ w1, const float* __restrict__ w2){
  long i = (long)blockIdx.x*256 + threadIdx.x;
  long stride = (long)gridDim.x*256;
  float* st = ws + OFF_STATE;
  for (long x = i; x < (long)STATE_N; x += stride) st[x] = 0.f;
  float* qWT = ws + OFF_QWT;     // [1024][128]
  for (long x = i; x < 1024*128; x += stride){ int u = x>>7, d = x&127; qWT[x] = qW[(size_t)d*1024+u]; }
  float* pWT = ws + OFF_PROJWT;  // [1536][80]
  for (long x = i; x < 1536*80; x += stride){ int k = x/80, m = x%80; pWT[x] = projW[(size_t)m*1536+k]; }
  float* mWT = ws + OFF_MWT;     // [512][128]
  for (long x = i; x < 512*128; x += stride){ int k = x>>7, d = x&127; mWT[x] = mW[(size_t)d*512+k]; }
  float* w1T = ws + OFF_W1T;     // [80][256]
  for (long x = i; x < 80*256; x += stride){ int m = x>>8, u = x&255; w1T[x] = w1[(size_t)u*80+m]; }
  float* w2T = ws + OFF_W2T;     // [256][256]
  for (long x = i; x < 256*256; x += stride){ int k = x>>8, u = x&255; w2T[x] = w2[(size_t)u*256+k]; }
}

// ---------------- prenet ----------------
__global__ __launch_bounds__(256) void k_prenet1(const float* __restrict__ di,
    const float* __restrict__ W1T, float* __restrict__ h1m, unsigned k10, unsigned k11){
  __shared__ float xs[NMEL];
  int bid = blockIdx.x;           // t*32 + b
  int t = bid >> 5, b = bid & 31;
  int tid = threadIdx.x;
  if (tid < NMEL) xs[tid] = (t == 0) ? 0.f : di[(size_t)b*40000 + (size_t)tid*500 + (t-1)];
  __syncthreads();
  float acc = 0.f;
  for (int m = 0; m < NMEL; ++m) acc += xs[m] * W1T[m*256 + tid];
  acc = fmaxf(acc, 0.f);
  unsigned idx = (unsigned)bid*256u + (unsigned)tid;
  h1m[(size_t)bid*256 + tid] = acc * mask_scale(k10, k11, idx);
}

__global__ __launch_bounds__(256) void k_prenet2(const float* __restrict__ h1m,
    const float* __restrict__ W2T, float* __restrict__ dec_ins, unsigned k20, unsigned k21){
  __shared__ float hs[PRE];
  int bid = blockIdx.x;
  int tid = threadIdx.x;
  hs[tid] = h1m[(size_t)bid*256 + tid];
  __syncthreads();
  float acc = 0.f;
  for (int k = 0; k < PRE; ++k) acc += hs[k] * W2T[k*256 + tid];
  acc = fmaxf(acc, 0.f);
  unsigned idx = (unsigned)bid*256u + (unsigned)tid;
  dec_ins[(size_t)bid*256 + tid] = acc * mask_scale(k20, k21, idx);
}

// ---------------- processed memory ----------------
__global__ __launch_bounds__(128) void k_procmem(const float* __restrict__ mem,
    const float* __restrict__ mWT, float* __restrict__ pm){
  __shared__ float ms[ENCD];
  int bid = blockIdx.x;  // b*300 + j
  int tid = threadIdx.x;
  const float* src = mem + (size_t)bid*ENCD;
  for (int i = tid; i < ENCD; i += 128) ms[i] = src[i];
  __syncthreads();
  float acc = 0.f;
  for (int k = 0; k < ENCD; ++k) acc += ms[k] * mWT[k*128 + tid];
  pm[(size_t)bid*128 + tid] = acc;
}

// ---------------- X source select (coherent, mutable inputs) ----------------
__device__ __forceinline__ const float* xsrc(const float* s0, int l0, const float* s1,
                                             const float* h, int b, int k){
  if (k < l0) return s0 + (size_t)b*l0 + k;
  if (k < l0 + 512) return s1 + (b<<9) + (k - l0);
  return h + (b<<10) + (k - (l0 + 512));
}

// ---------------- fused LSTM block: 4 units (16 rows) x full K -> cell update ----------------
// block ub owns units ub*4..ub*4+3. Writes c_st (exclusive) and hnew[b*1024+unit].
__device__ __forceinline__ void lstm_block(int ub,
    const float* __restrict__ W1, const float* __restrict__ W2,
    const float* __restrict__ bih, const float* __restrict__ bhh,
    const float* __restrict__ s0, int l0, const float* __restrict__ s1,
    const float* __restrict__ hprev, int Ktot,
    float* __restrict__ c_st, float* __restrict__ hnew, int tid){
  __shared__ float Xc[2][128*32];       // [chunk k][b], XOR-swizzled slots
  __shared__ float gates[16][32];
  const int xw = l0 + 512, xw4 = xw >> 2;
  const int NC = Ktot >> 7;             // K chunks of 128 (14 att, 20 dec)
  const int w = tid >> 6, l = tid & 63;
  const int ss = l & 31, ph = l >> 5;
  const int phat = w*2 + ph;            // row-pair 0..7
  const int rlA = 2*phat, rlB = rlA + 1;
  const int rowA = (rlA >> 2)*1024 + ub*4 + (rlA & 3);
  const int rowB = (rlB >> 2)*1024 + ub*4 + (rlB & 3);
  const float4* W1A = (const float4*)(W1 + (size_t)rowA*xw);
  const float4* W1B = (const float4*)(W1 + (size_t)rowB*xw);
  const float4* W2A = (const float4*)(W2 + ((size_t)rowA<<10));
  const float4* W2B = (const float4*)(W2 + ((size_t)rowB<<10));
  float accA[32] = {}, accB[32] = {};
  float2 sx[8];
  // stage chunk 0
#pragma unroll
  for (int it = 0; it < 8; ++it){
    int pidx = tid + it*256;
    int b = pidx >> 6, kL = (pidx & 63)*2;
    sx[it] = gload2(xsrc(s0, l0, s1, hprev, b, kL));
  }
#pragma unroll
  for (int it = 0; it < 8; ++it){
    int pidx = tid + it*256;
    int b = pidx >> 6, kL = (pidx & 63)*2;
    int a0 = kL*32 + (((b>>2) ^ ((kL>>2)&7))<<2) + (b&3);
    Xc[0][a0] = sx[it].x; Xc[0][a0+32] = sx[it].y;
  }
  float4 wA, wB;
  { int f = ss;
    wA = (f < xw4) ? W1A[f] : W2A[f - xw4];
    wB = (f < xw4) ? W1B[f] : W2B[f - xw4]; }
  __syncthreads();

  for (int c = 0; c < NC; ++c){
    float4 wAn, wBn;
    if (c + 1 < NC){
      int f = (c+1)*32 + ss;
      wAn = (f < xw4) ? W1A[f] : W2A[f - xw4];
      wBn = (f < xw4) ? W1B[f] : W2B[f - xw4];
      int kg0 = (c+1) << 7;
#pragma unroll
      for (int it = 0; it < 8; ++it){
        int pidx = tid + it*256;
        int b = pidx >> 6, kL = (pidx & 63)*2;
        sx[it] = gload2(xsrc(s0, l0, s1, hprev, b, kg0 + kL));
      }
    }
    const float4* X4 = (const float4*)Xc[c & 1];
    const int sw = ss & 7;
#pragma unroll
    for (int e = 0; e < 4; ++e){
      int kL = 4*ss + e;
      float ea = (e==0)?wA.x:(e==1)?wA.y:(e==2)?wA.z:wA.w;
      float eb = (e==0)?wB.x:(e==1)?wB.y:(e==2)?wB.z:wB.w;
      int base = kL*8;
#pragma unroll
      for (int b0 = 0; b0 < 8; ++b0){
        float4 xv = X4[base + (b0 ^ sw)];
        accA[4*b0+0] += ea*xv.x; accA[4*b0+1] += ea*xv.y;
        accA[4*b0+2] += ea*xv.z; accA[4*b0+3] += ea*xv.w;
        accB[4*b0+0] += eb*xv.x; accB[4*b0+1] += eb*xv.y;
        accB[4*b0+2] += eb*xv.z; accB[4*b0+3] += eb*xv.w;
      }
    }
    if (c + 1 < NC){
#pragma unroll
      for (int it = 0; it < 8; ++it){
        int pidx = tid + it*256;
        int b = pidx >> 6, kL = (pidx & 63)*2;
        int a0 = kL*32 + (((b>>2) ^ ((kL>>2)&7))<<2) + (b&3);
        Xc[(c+1)&1][a0] = sx[it].x; Xc[(c+1)&1][a0+32] = sx[it].y;
      }
      wA = wAn; wB = wBn;
    }
    __syncthreads();
  }
  // reduce-scatter over ss (lane ends with b = ss)
#pragma unroll
  for (int m = 16; m >= 1; m >>= 1){
    int up = ss & m;
#pragma unroll
    for (int j = 0; j < m; ++j){
      float sA = up ? accA[j] : accA[j+m];
      float kA = up ? accA[j+m] : accA[j];
      float sB = up ? accB[j] : accB[j+m];
      float kB = up ? accB[j+m] : accB[j];
      accA[j] = kA + __shfl_xor(sA, m, 64);
      accB[j] = kB + __shfl_xor(sB, m, 64);
    }
  }
  gates[rlA][ss] = accA[0];
  gates[rlB][ss] = accB[0];
  __syncthreads();
  if (tid < 128){
    int b = tid & 31, u = tid >> 5;
    int gu = ub*4 + u;
    float gi = gates[u][b]     + bih[gu]         + bhh[gu];
    float gf = gates[4+u][b]   + bih[1024+gu]    + bhh[1024+gu];
    float gg = gates[8+u][b]   + bih[2048+gu]    + bhh[2048+gu];
    float go = gates[12+u][b]  + bih[3072+gu]    + bhh[3072+gu];
    float ii = 1.f/(1.f + expf(-gi));
    float ff = 1.f/(1.f + expf(-gf));
    float oo = 1.f/(1.f + expf(-go));
    float tg = tanhf(gg);
    float cold = gload(&c_st[b*1024 + gu]);
    float cn = ff*cold + ii*tg;
    gstore(&c_st[b*1024 + gu], cn);
    gstore(&hnew[b*1024 + gu], oo*tanhf(cn));
  }
  __syncthreads();
}

// ---------------- energy tile (16 j's) ----------------
__device__ __forceinline__ void energy_tile(int b, int tile,
    const float* __restrict__ aw, const float* __restrict__ awc,
    const float* __restrict__ lcW, const float* __restrict__ ldW, const float* __restrict__ vw,
    const float* __restrict__ sPq, const float* __restrict__ pm, float* __restrict__ e_ws, int tid){
  __shared__ float sIn[2][46];
  __shared__ float cfs[16][33];
  __shared__ float ep[16][17];
  int j0 = tile*16;
  if (tid < 46){ int j = j0 - 15 + tid; sIn[0][tid] = (j >= 0 && j < 300) ? gload(&aw[b*300 + j]) : 0.f; }
  else if (tid < 92){ int i = tid - 46; int j = j0 - 15 + i; sIn[1][i] = (j >= 0 && j < 300) ? gload(&awc[b*300 + j]) : 0.f; }
  __syncthreads();
  { int fg = tid & 15, jl = tid >> 4;
    int f0 = 2*fg;
    float c0 = 0.f, c1 = 0.f;
#pragma unroll
    for (int c = 0; c < 2; ++c)
#pragma unroll
      for (int k = 0; k < 31; ++k){
        float a = sIn[c][jl + k];
        c0 += a * lcW[f0*62 + c*31 + k];
        c1 += a * lcW[(f0+1)*62 + c*31 + k];
      }
    cfs[jl][f0] = c0; cfs[jl][f0+1] = c1;
  }
  __syncthreads();
  { int dg = tid & 15, jl = tid >> 4;
    int j = j0 + jl;
    float s = 0.f;
    if (j < 300){
      const float* pmrow = pm + ((size_t)(b*300 + j))*128 + dg*8;
#pragma unroll
      for (int dd = 0; dd < 8; ++dd){
        int d = dg*8 + dd;
        float acc = sPq[d] + pmrow[dd];
#pragma unroll
        for (int f = 0; f < 32; ++f) acc += cfs[jl][f] * ldW[d*32 + f];
        s += vw[d] * tanhf(acc);
      }
    }
    ep[jl][dg] = s;
  }
  __syncthreads();
  if (tid < 16){
    int j = j0 + tid;
    if (j < 300){
      float s = 0.f;
#pragma unroll
      for (int dg = 0; dg < 16; ++dg) s += ep[tid][dg];
      gstore(&e_ws[b*300 + j], s);
    }
  }
  __syncthreads();
}

// ---------------- B: pq + energy slices ----------------
__device__ __forceinline__ void pq_energy(int b, int jt, const float* __restrict__ ah,
    const float* __restrict__ qWT, const float* __restrict__ aw, const float* __restrict__ awc,
    const float* __restrict__ lcW, const float* __restrict__ ldW, const float* __restrict__ vw,
    const float* __restrict__ pm, float* __restrict__ e_ws, int tid){
  __shared__ float sAh[1024];
  __shared__ float pqs[256];
  __shared__ float sPq[128];
  for (int i = tid; i < 1024; i += 256) sAh[i] = gload(&ah[b*1024 + i]);
  __syncthreads();
  int d = tid & 127, half = tid >> 7;
  const float* qt = qWT + (size_t)(half*512)*128 + d;
  float acc = 0.f;
  for (int u = 0; u < 512; ++u) acc += sAh[half*512 + u] * qt[(size_t)u*128];
  pqs[half*128 + d] = acc;
  __syncthreads();
  if (tid < 128) sPq[tid] = pqs[tid] + pqs[128 + tid];
  __syncthreads();
  for (int tile = jt; tile < 19; tile += 8)
    energy_tile(b, tile, aw, awc, lcW, ldW, vw, sPq, pm, e_ws, tid);
}

// ---------------- C: softmax + ctx (8-way d-split) ----------------
__device__ __forceinline__ void soft_phase(int b, int dsl, const float* __restrict__ e_ws,
    const int* __restrict__ lens, const float* __restrict__ mem,
    float* __restrict__ aw, float* __restrict__ awc, float* __restrict__ ctx,
    float* __restrict__ out, int t, int tid){
  __shared__ float se[300];
  __shared__ float sa[300];
  __shared__ float red[256];
  int len = lens[b];
  for (int j = tid; j < 300; j += 256) se[j] = gload(&e_ws[b*300 + j]);
  __syncthreads();
  float m = -1e30f;
  for (int j = tid; j < len; j += 256) m = fmaxf(m, se[j]);
  red[tid] = m; __syncthreads();
  for (int s = 128; s > 0; s >>= 1){ if (tid < s) red[tid] = fmaxf(red[tid], red[tid + s]); __syncthreads(); }
  float mx = red[0]; __syncthreads();
  float ssum = 0.f;
  for (int j = tid; j < len; j += 256) ssum += expf(se[j] - mx);
  red[tid] = ssum; __syncthreads();
  for (int s = 128; s > 0; s >>= 1){ if (tid < s) red[tid] += red[tid + s]; __syncthreads(); }
  float inv = 1.f/red[0];
  __syncthreads();
  float* al = out + 1296000 + (size_t)b*150000 + (size_t)t*300;
  for (int j = tid; j < 300; j += 256){
    float v = (j < len) ? expf(se[j] - mx)*inv : 0.f;
    sa[j] = v;
    if (dsl == 0){
      gstore(&aw[b*300 + j], v);
      gstore(&awc[b*300 + j], gload(&awc[b*300 + j]) + v);
      al[j] = v;
    }
  }
  __syncthreads();
  int d = dsl*64 + (tid & 63), jq = tid >> 6;
  int chunk = (len + 3) >> 2;
  int j0 = jq*chunk, j1 = min(len, j0 + chunk);
  float acc = 0.f;
  const float* mb = mem + (size_t)b*153600 + d;
  for (int j = j0; j < j1; ++j) acc += sa[j]*mb[(size_t)j*512];
  red[tid] = acc; __syncthreads();
  if (jq == 0) gstore(&ctx[b*512 + d], red[tid] + red[tid+64] + red[tid+128] + red[tid+192]);
  __syncthreads();
}

// ---------------- E: mel + gate outputs ----------------
__device__ __forceinline__ void dec_out(int b, const float* __restrict__ dh, const float* __restrict__ ctx,
    const float* __restrict__ pWT, const float* __restrict__ projb,
    const float* __restrict__ gateW, const float* __restrict__ gateb,
    float* __restrict__ out, int t, int tid){
  __shared__ float sDh[1024];
  __shared__ float sCtx[512];
  __shared__ float red[256];
  __shared__ float melp[3][80];
  for (int i = tid; i < 1024; i += 256) sDh[i] = gload(&dh[b*1024 + i]);
  for (int i = tid; i < 512; i += 256) sCtx[i] = gload(&ctx[b*512 + i]);
  __syncthreads();
  if (tid < 240){
    int m = tid % 80, seg = tid / 80;
    float mp = 0.f;
    for (int k = seg*512; k < seg*512 + 512; ++k){
      float x = (k < 1024) ? sDh[k] : sCtx[k - 1024];
      mp += x * pWT[(size_t)k*80 + m];
    }
    melp[seg][m] = mp;
  }
  float g = 0.f;
  for (int k = tid; k < 1536; k += 256){
    float x = (k < 1024) ? sDh[k] : sCtx[k - 1024];
    g += x * gateW[k];
  }
  red[tid] = g; __syncthreads();
  for (int s = 128; s > 0; s >>= 1){ if (tid < s) red[tid] += red[tid + s]; __syncthreads(); }
  if (tid == 0) out[1280000 + (size_t)b*500 + t] = red[0] + gateb[0];
  if (tid < 80){
    float mel = melp[0][tid] + melp[1][tid] + melp[2][tid] + projb[tid];
    out[(size_t)b*40000 + (size_t)tid*500 + t] = mel;
  }
  __syncthreads();
}

// ---------------- persistent loop ----------------
struct DecParams {
  const float *memory;
  const int   *lens;
  const float *attWih, *attWhh, *attBih, *attBhh;
  const float *decWih, *decWhh, *decBih, *decBhh;
  const float *lcW, *ldW, *vw, *projb, *gateW, *gateb;
  float *ws, *out;
};

__global__ void __launch_bounds__(256, 1) k_loop(DecParams p){
  int wg = blockIdx.x, tid = threadIdx.x;
  float* ws = p.ws;
  float* decins = ws + OFF_DECINS;
  float* e_ws = ws + OFF_E;
  float* pm = ws + OFF_PM;
  float* AH[2] = { ws + OFF_AH0, ws + OFF_AH1 };
  float* DH[2] = { ws + OFF_DH0, ws + OFF_DH1 };
  float* AC = ws + OFF_AC;
  float* DC = ws + OFF_DC;
  float* ctx = ws + OFF_CTX;
  float* aw = ws + OFF_AW;
  float* awc = ws + OFF_AWC;
  float* qWT = ws + OFF_QWT;
  float* pWT = ws + OFF_PROJWT;
  unsigned* slots = (unsigned*)(ws + OFF_SLOTS);
  unsigned* gen = slots + 4096;
  unsigned ep = 0;

  // A for t=0: ah(1) = LSTM([x_0, ctx_0=0], ah(0)=0)
  lstm_block(wg, p.attWih, p.attWhh, p.attBih, p.attBhh,
             decins, PRE, ctx, AH[0], 1792, AC, AH[1], tid);
  gbar(slots, gen, ++ep);

  for (int t = 0; t < TDEC; ++t){
    int cu = (t + 1) & 1, pr = t & 1;
    // B: pq + energy  [b = wg>>3, jt = wg&7]
    pq_energy(wg >> 3, wg & 7, AH[cu], qWT, aw, awc, p.lcW, p.ldW, p.vw, pm, e_ws, tid);
    gbar(slots, gen, ++ep);
    // C: softmax + ctx  [b = wg>>3, dslice = wg&7]
    soft_phase(wg >> 3, wg & 7, e_ws, p.lens, p.memory, aw, awc, ctx, p.out, t, tid);
    gbar(slots, gen, ++ep);
    // D: dec LSTM fused
    lstm_block(wg, p.decWih, p.decWhh, p.decBih, p.decBhh,
               AH[cu], 1024, ctx, DH[pr], 2560, DC, DH[cu], tid);
    gbar(slots, gen, ++ep);
    // E (32 blocks) then A(t+1) (all blocks)
    if (wg < 32)
      dec_out(wg, DH[cu], ctx, pWT, p.projb, p.gateW, p.gateb, p.out, t, tid);
    if (t + 1 < TDEC)
      lstm_block(wg, p.attWih, p.attWhh, p.attBih, p.attBhh,
                 decins + (size_t)(t + 1)*NB*PRE, PRE, ctx, AH[cu], 1792, AC, AH[pr], tid);
    gbar(slots, gen, ++ep);
  }
}

// ---------------- host ----------------
extern "C" void kernel_launch(void* const* d_in, const int* in_sizes, int n_in,
                              void* d_out, int out_size, void* d_ws, size_t ws_size,
                              hipStream_t stream) {
  const float* memory   = (const float*)d_in[0];
  const float* dec_in   = (const float*)d_in[1];
  const int*   lens     = (const int*)  d_in[2];
  const float* pre_W1   = (const float*)d_in[3];
  const float* pre_W2   = (const float*)d_in[4];
  const float* att_Wih  = (const float*)d_in[5];
  const float* att_Whh  = (const float*)d_in[6];
  const float* att_bih  = (const float*)d_in[7];
  const float* att_bhh  = (const float*)d_in[8];
  const float* q_W      = (const float*)d_in[9];
  const float* m_W      = (const float*)d_in[10];
  const float* v_w      = (const float*)d_in[11];
  const float* lc_W     = (const float*)d_in[12];
  const float* ld_W     = (const float*)d_in[13];
  const float* dec_Wih  = (const float*)d_in[14];
  const float* dec_Whh  = (const float*)d_in[15];
  const float* dec_bih  = (const float*)d_in[16];
  const float* dec_bhh  = (const float*)d_in[17];
  const float* proj_W   = (const float*)d_in[18];
  const float* proj_b   = (const float*)d_in[19];
  const float* gate_W   = (const float*)d_in[20];
  const float* gate_b   = (const float*)d_in[21];
  float* out = (float*)d_out;
  float* ws  = (float*)d_ws;

  // Partitionable (foldlike) split of jax.random.key(1)
  unsigned k10, k11, k20, k21;
  tf2x32(0u, 1u, 0u, 0u, k10, k11);
  tf2x32(0u, 1u, 0u, 1u, k20, k21);

  k_setup<<<1024, 256, 0, stream>>>(ws, q_W, proj_W, m_W, pre_W1, pre_W2);
  k_prenet1<<<TDEC*NB, 256, 0, stream>>>(dec_in, ws + OFF_W1T, ws + OFF_H1M, k10, k11);
  k_prenet2<<<TDEC*NB, 256, 0, stream>>>(ws + OFF_H1M, ws + OFF_W2T, ws + OFF_DECINS, k20, k21);
  k_procmem<<<NB*TENC, 128, 0, stream>>>(memory, ws + OFF_MWT, ws + OFF_PM);

  DecParams hp;
  hp.memory = memory; hp.lens = lens;
  hp.attWih = att_Wih; hp.attWhh = att_Whh; hp.attBih = att_bih; hp.attBhh = att_bhh;
  hp.decWih = dec_Wih; hp.decWhh = dec_Whh; hp.decBih = dec_bih; hp.decBhh = dec_bhh;
  hp.lcW = lc_W; hp.ldW = ld_W; hp.vw = v_w; hp.projb = proj_b; hp.gateW = gate_W; hp.gateb = gate_b;
  hp.ws = ws; hp.out = out;
  k_loop<<<256, 256, 0, stream>>>(hp);
}

// Round 8
// 187392.065 us; speedup vs baseline: 2.0069x; 1.0173x over previous
//
#include <hip/hip_runtime.h>

#define NB 32
#define TENC 300
#define TDEC 500
#define NMEL 80
#define ENCD 512
#define PRE 256
#define ADIM 128
#define RD 8          // ring depth

// ---------------- workspace layout (float offsets) ----------------
#define OFF_DECINS 0ull                         // 500*32*256 = 4,096,000
#define OFF_H1M    4096000ull                   // prenet scratch (pre-loop only)
// rings alias the H1M region (H1M dead once k_loop starts)
#define OFF_AHR    4096000ull                   // 8*32768 = 262,144
#define OFF_DHR    (OFF_AHR + 262144ull)        // 262,144
#define OFF_CXR    (OFF_DHR + 262144ull)        // 8*16384 = 131,072
#define RINGS_N    655360ull
#define OFF_PM     8192000ull                   // 32*300*128 = 1,228,800
#define OFF_STATE  (OFF_PM + 1228800ull)        // = 9,420,800
#define OFF_AC     (OFF_STATE + 0ull)           // 32,768
#define OFF_DC     (OFF_STATE + 32768ull)       // 32,768
#define OFF_AW     (OFF_STATE + 65536ull)       // 9,600
#define OFF_AWC    (OFF_STATE + 75136ull)       // 9,600
#define OFF_E      (OFF_STATE + 84736ull)       // 9,600
#define OFF_SLOTS  (OFF_STATE + 94336ull)       // 4,104 u32
#define STATE_N    98440ull
#define OFF_QWT    (OFF_STATE + STATE_N)        // 131,072
#define OFF_PROJWT (OFF_QWT + 131072ull)        // 122,880
#define OFF_MWT    (OFF_PROJWT + 122880ull)     // 65,536
#define OFF_W1T    (OFF_MWT + 65536ull)         // 20,480
#define OFF_W2T    (OFF_W1T + 20480ull)         // 65,536

// ---------------- device-coherent (agent-scope, fence-free) helpers ----------------
__device__ __forceinline__ float gload(const float* p){
  return __hip_atomic_load(p, __ATOMIC_RELAXED, __HIP_MEMORY_SCOPE_AGENT);
}
__device__ __forceinline__ void gstore(float* p, float v){
  __hip_atomic_store(p, v, __ATOMIC_RELAXED, __HIP_MEMORY_SCOPE_AGENT);
}

// ---------------- contention-free grid barrier ----------------
__device__ __forceinline__ void gbar(unsigned* slots, unsigned* gen, unsigned epoch){
  int wg = blockIdx.x, tid = threadIdx.x;
  __syncthreads();
  if (wg == 0){
    if (tid != 0){
      while (__hip_atomic_load(&slots[tid*16], __ATOMIC_RELAXED, __HIP_MEMORY_SCOPE_AGENT) < epoch)
        __builtin_amdgcn_s_sleep(8);
    }
    __syncthreads();
    if (tid == 0)
      __hip_atomic_store(gen, epoch, __ATOMIC_RELAXED, __HIP_MEMORY_SCOPE_AGENT);
  } else {
    if (tid == 0){
      __hip_atomic_store(&slots[wg*16], epoch, __ATOMIC_RELAXED, __HIP_MEMORY_SCOPE_AGENT);
      while (__hip_atomic_load(gen, __ATOMIC_RELAXED, __HIP_MEMORY_SCOPE_AGENT) < epoch)
        __builtin_amdgcn_s_sleep(8);
    }
    __syncthreads();
  }
}

// ---------------- threefry2x32 (matches JAX bit-exactly) ----------------
__host__ __device__ __forceinline__ unsigned rotl32(unsigned v, int r){ return (v<<r)|(v>>(32-r)); }

__host__ __device__ __forceinline__ void tf2x32(unsigned k0, unsigned k1, unsigned c0, unsigned c1,
                                                unsigned& y0, unsigned& y1){
  unsigned ks2 = k0 ^ k1 ^ 0x1BD11BDAu;
  unsigned x0 = c0 + k0, x1 = c1 + k1;
#define TFR(r) x0 += x1; x1 = rotl32(x1, r); x1 ^= x0;
  TFR(13) TFR(15) TFR(26) TFR(6)
  x0 += k1;  x1 += ks2 + 1u;
  TFR(17) TFR(29) TFR(16) TFR(24)
  x0 += ks2; x1 += k0 + 2u;
  TFR(13) TFR(15) TFR(26) TFR(6)
  x0 += k0;  x1 += k1 + 3u;
  TFR(17) TFR(29) TFR(16) TFR(24)
  x0 += k1;  x1 += ks2 + 4u;
  TFR(13) TFR(15) TFR(26) TFR(6)
  x0 += ks2; x1 += k0 + 5u;
#undef TFR
  y0 = x0; y1 = x1;
}

__device__ __forceinline__ float mask_scale(unsigned k0, unsigned k1, unsigned idx){
  unsigned y0, y1;
  tf2x32(k0, k1, 0u, idx, y0, y1);
  unsigned bits = y0 ^ y1;
  float u = __uint_as_float((bits >> 9) | 0x3f800000u) - 1.0f;
  return (u < 0.9f) ? (1.0f/0.9f) : 0.0f;
}

// ---------------- setup: zero small state + slots, weight transposes ----------------
__global__ __launch_bounds__(256) void k_setup(float* __restrict__ ws,
    const float* __restrict__ qW, const float* __restrict__ projW, const float* __restrict__ mW,
    const float* __restrict__ w1, const float* __restrict__ w2){
  long i = (long)blockIdx.x*256 + threadIdx.x;
  long stride = (long)gridDim.x*256;
  float* st = ws + OFF_STATE;
  for (long x = i; x < (long)STATE_N; x += stride) st[x] = 0.f;
  float* qWT = ws + OFF_QWT;     // [1024][128]
  for (long x = i; x < 1024*128; x += stride){ int u = x>>7, d = x&127; qWT[x] = qW[(size_t)d*1024+u]; }
  float* pWT = ws + OFF_PROJWT;  // [1536][80]
  for (long x = i; x < 1536*80; x += stride){ int k = x/80, m = x%80; pWT[x] = projW[(size_t)m*1536+k]; }
  float* mWT = ws + OFF_MWT;     // [512][128]
  for (long x = i; x < 512*128; x += stride){ int k = x>>7, d = x&127; mWT[x] = mW[(size_t)d*512+k]; }
  float* w1T = ws + OFF_W1T;     // [80][256]
  for (long x = i; x < 80*256; x += stride){ int m = x>>8, u = x&255; w1T[x] = w1[(size_t)u*80+m]; }
  float* w2T = ws + OFF_W2T;     // [256][256]
  for (long x = i; x < 256*256; x += stride){ int k = x>>8, u = x&255; w2T[x] = w2[(size_t)u*256+k]; }
}

// ---------------- prenet ----------------
__global__ __launch_bounds__(256) void k_prenet1(const float* __restrict__ di,
    const float* __restrict__ W1T, float* __restrict__ h1m, unsigned k10, unsigned k11){
  __shared__ float xs[NMEL];
  int bid = blockIdx.x;           // t*32 + b
  int t = bid >> 5, b = bid & 31;
  int tid = threadIdx.x;
  if (tid < NMEL) xs[tid] = (t == 0) ? 0.f : di[(size_t)b*40000 + (size_t)tid*500 + (t-1)];
  __syncthreads();
  float acc = 0.f;
  for (int m = 0; m < NMEL; ++m) acc += xs[m] * W1T[m*256 + tid];
  acc = fmaxf(acc, 0.f);
  unsigned idx = (unsigned)bid*256u + (unsigned)tid;
  h1m[(size_t)bid*256 + tid] = acc * mask_scale(k10, k11, idx);
}

__global__ __launch_bounds__(256) void k_prenet2(const float* __restrict__ h1m,
    const float* __restrict__ W2T, float* __restrict__ dec_ins, unsigned k20, unsigned k21){
  __shared__ float hs[PRE];
  int bid = blockIdx.x;
  int tid = threadIdx.x;
  hs[tid] = h1m[(size_t)bid*256 + tid];
  __syncthreads();
  float acc = 0.f;
  for (int k = 0; k < PRE; ++k) acc += hs[k] * W2T[k*256 + tid];
  acc = fmaxf(acc, 0.f);
  unsigned idx = (unsigned)bid*256u + (unsigned)tid;
  dec_ins[(size_t)bid*256 + tid] = acc * mask_scale(k20, k21, idx);
}

// ---------------- processed memory ----------------
__global__ __launch_bounds__(128) void k_procmem(const float* __restrict__ mem,
    const float* __restrict__ mWT, float* __restrict__ pm){
  __shared__ float ms[ENCD];
  int bid = blockIdx.x;  // b*300 + j
  int tid = threadIdx.x;
  const float* src = mem + (size_t)bid*ENCD;
  for (int i = tid; i < ENCD; i += 128) ms[i] = src[i];
  __syncthreads();
  float acc = 0.f;
  for (int k = 0; k < ENCD; ++k) acc += ms[k] * mWT[k*128 + tid];
  pm[(size_t)bid*128 + tid] = acc;
}

// ---------------- X source (CACHED loads; ring buffers make this safe) ----------------
__device__ __forceinline__ float2 xld2(const float* s0, int l0, const float* s1,
                                       const float* h, int b, int k){
  const float* p;
  if (k < l0) p = s0 + (size_t)b*l0 + k;
  else if (k < l0 + 512) p = s1 + (b<<9) + (k - l0);
  else p = h + (b<<10) + (k - (l0 + 512));
  return *(const float2*)p;
}

// ---------------- fused LSTM block: 4 units (16 rows) x full K -> cell update ----------------
__device__ __forceinline__ void lstm_block(int ub,
    const float* __restrict__ W1, const float* __restrict__ W2,
    const float* __restrict__ bih, const float* __restrict__ bhh,
    const float* __restrict__ s0, int l0, const float* __restrict__ s1,
    const float* __restrict__ hprev, int Ktot,
    float* __restrict__ c_st, float* __restrict__ hnew, int tid){
  __shared__ float Xc[2][128*32];       // [chunk k][b], XOR-swizzled slots
  __shared__ float gates[16][32];
  const int xw = l0 + 512, xw4 = xw >> 2;
  const int NC = Ktot >> 7;             // K chunks of 128 (14 att, 20 dec)
  const int w = tid >> 6, l = tid & 63;
  const int ss = l & 31, ph = l >> 5;
  const int phat = w*2 + ph;            // row-pair 0..7
  const int rlA = 2*phat, rlB = rlA + 1;
  const int rowA = (rlA >> 2)*1024 + ub*4 + (rlA & 3);
  const int rowB = (rlB >> 2)*1024 + ub*4 + (rlB & 3);
  const float4* W1A = (const float4*)(W1 + (size_t)rowA*xw);
  const float4* W1B = (const float4*)(W1 + (size_t)rowB*xw);
  const float4* W2A = (const float4*)(W2 + ((size_t)rowA<<10));
  const float4* W2B = (const float4*)(W2 + ((size_t)rowB<<10));
  float accA[32] = {}, accB[32] = {};
  float2 sx[8];
  // stage chunk 0
#pragma unroll
  for (int it = 0; it < 8; ++it){
    int pidx = tid + it*256;
    int b = pidx >> 6, kL = (pidx & 63)*2;
    sx[it] = xld2(s0, l0, s1, hprev, b, kL);
  }
#pragma unroll
  for (int it = 0; it < 8; ++it){
    int pidx = tid + it*256;
    int b = pidx >> 6, kL = (pidx & 63)*2;
    int a0 = kL*32 + (((b>>2) ^ ((kL>>2)&7))<<2) + (b&3);
    Xc[0][a0] = sx[it].x; Xc[0][a0+32] = sx[it].y;
  }
  float4 wA, wB;
  { int f = ss;
    wA = (f < xw4) ? W1A[f] : W2A[f - xw4];
    wB = (f < xw4) ? W1B[f] : W2B[f - xw4]; }
  __syncthreads();

  for (int c = 0; c < NC; ++c){
    float4 wAn, wBn;
    if (c + 1 < NC){
      int f = (c+1)*32 + ss;
      wAn = (f < xw4) ? W1A[f] : W2A[f - xw4];
      wBn = (f < xw4) ? W1B[f] : W2B[f - xw4];
      int kg0 = (c+1) << 7;
#pragma unroll
      for (int it = 0; it < 8; ++it){
        int pidx = tid + it*256;
        int b = pidx >> 6, kL = (pidx & 63)*2;
        sx[it] = xld2(s0, l0, s1, hprev, b, kg0 + kL);
      }
    }
    const float4* X4 = (const float4*)Xc[c & 1];
    const int sw = ss & 7;
#pragma unroll
    for (int e = 0; e < 4; ++e){
      int kL = 4*ss + e;
      float ea = (e==0)?wA.x:(e==1)?wA.y:(e==2)?wA.z:wA.w;
      float eb = (e==0)?wB.x:(e==1)?wB.y:(e==2)?wB.z:wB.w;
      int base = kL*8;
#pragma unroll
      for (int b0 = 0; b0 < 8; ++b0){
        float4 xv = X4[base + (b0 ^ sw)];
        accA[4*b0+0] += ea*xv.x; accA[4*b0+1] += ea*xv.y;
        accA[4*b0+2] += ea*xv.z; accA[4*b0+3] += ea*xv.w;
        accB[4*b0+0] += eb*xv.x; accB[4*b0+1] += eb*xv.y;
        accB[4*b0+2] += eb*xv.z; accB[4*b0+3] += eb*xv.w;
      }
    }
    if (c + 1 < NC){
#pragma unroll
      for (int it = 0; it < 8; ++it){
        int pidx = tid + it*256;
        int b = pidx >> 6, kL = (pidx & 63)*2;
        int a0 = kL*32 + (((b>>2) ^ ((kL>>2)&7))<<2) + (b&3);
        Xc[(c+1)&1][a0] = sx[it].x; Xc[(c+1)&1][a0+32] = sx[it].y;
      }
      wA = wAn; wB = wBn;
    }
    __syncthreads();
  }
  // reduce-scatter over ss (lane ends with b = ss)
#pragma unroll
  for (int m = 16; m >= 1; m >>= 1){
    int up = ss & m;
#pragma unroll
    for (int j = 0; j < m; ++j){
      float sA = up ? accA[j] : accA[j+m];
      float kA = up ? accA[j+m] : accA[j];
      float sB = up ? accB[j] : accB[j+m];
      float kB = up ? accB[j+m] : accB[j];
      accA[j] = kA + __shfl_xor(sA, m, 64);
      accB[j] = kB + __shfl_xor(sB, m, 64);
    }
  }
  gates[rlA][ss] = accA[0];
  gates[rlB][ss] = accB[0];
  __syncthreads();
  if (tid < 128){
    int b = tid & 31, u = tid >> 5;
    int gu = ub*4 + u;
    float gi = gates[u][b]     + bih[gu]         + bhh[gu];
    float gf = gates[4+u][b]   + bih[1024+gu]    + bhh[1024+gu];
    float gg = gates[8+u][b]   + bih[2048+gu]    + bhh[2048+gu];
    float go = gates[12+u][b]  + bih[3072+gu]    + bhh[3072+gu];
    float ii = 1.f/(1.f + expf(-gi));
    float ff = 1.f/(1.f + expf(-gf));
    float oo = 1.f/(1.f + expf(-go));
    float tg = tanhf(gg);
    float cold = gload(&c_st[b*1024 + gu]);
    float cn = ff*cold + ii*tg;
    gstore(&c_st[b*1024 + gu], cn);
    gstore(&hnew[b*1024 + gu], oo*tanhf(cn));
  }
  __syncthreads();
}

// ---------------- energy tile (16 j's) ----------------
__device__ __forceinline__ void energy_tile(int b, int tile,
    const float* __restrict__ aw, const float* __restrict__ awc,
    const float* __restrict__ lcW, const float* __restrict__ ldW, const float* __restrict__ vw,
    const float* __restrict__ sPq, const float* __restrict__ pm, float* __restrict__ e_ws, int tid){
  __shared__ float sIn[2][46];
  __shared__ float cfs[16][33];
  __shared__ float ep[16][17];
  int j0 = tile*16;
  if (tid < 46){ int j = j0 - 15 + tid; sIn[0][tid] = (j >= 0 && j < 300) ? gload(&aw[b*300 + j]) : 0.f; }
  else if (tid < 92){ int i = tid - 46; int j = j0 - 15 + i; sIn[1][i] = (j >= 0 && j < 300) ? gload(&awc[b*300 + j]) : 0.f; }
  __syncthreads();
  { int fg = tid & 15, jl = tid >> 4;
    int f0 = 2*fg;
    float c0 = 0.f, c1 = 0.f;
#pragma unroll
    for (int c = 0; c < 2; ++c)
#pragma unroll
      for (int k = 0; k < 31; ++k){
        float a = sIn[c][jl + k];
        c0 += a * lcW[f0*62 + c*31 + k];
        c1 += a * lcW[(f0+1)*62 + c*31 + k];
      }
    cfs[jl][f0] = c0; cfs[jl][f0+1] = c1;
  }
  __syncthreads();
  { int dg = tid & 15, jl = tid >> 4;
    int j = j0 + jl;
    float s = 0.f;
    if (j < 300){
      const float* pmrow = pm + ((size_t)(b*300 + j))*128 + dg*8;
#pragma unroll
      for (int dd = 0; dd < 8; ++dd){
        int d = dg*8 + dd;
        float acc = sPq[d] + pmrow[dd];
#pragma unroll
        for (int f = 0; f < 32; ++f) acc += cfs[jl][f] * ldW[d*32 + f];
        s += vw[d] * tanhf(acc);
      }
    }
    ep[jl][dg] = s;
  }
  __syncthreads();
  if (tid < 16){
    int j = j0 + tid;
    if (j < 300){
      float s = 0.f;
#pragma unroll
      for (int dg = 0; dg < 16; ++dg) s += ep[tid][dg];
      gstore(&e_ws[b*300 + j], s);
    }
  }
  __syncthreads();
}

// ---------------- B: pq + energy slices ----------------
__device__ __forceinline__ void pq_energy(int b, int jt, const float* __restrict__ ah,
    const float* __restrict__ qWT, const float* __restrict__ aw, const float* __restrict__ awc,
    const float* __restrict__ lcW, const float* __restrict__ ldW, const float* __restrict__ vw,
    const float* __restrict__ pm, float* __restrict__ e_ws, int tid){
  __shared__ float sAh[1024];
  __shared__ float pqs[256];
  __shared__ float sPq[128];
  for (int i = tid; i < 1024; i += 256) sAh[i] = ah[b*1024 + i];   // cached (ring slot)
  __syncthreads();
  int d = tid & 127, half = tid >> 7;
  const float* qt = qWT + (size_t)(half*512)*128 + d;
  float acc = 0.f;
  for (int u = 0; u < 512; ++u) acc += sAh[half*512 + u] * qt[(size_t)u*128];
  pqs[half*128 + d] = acc;
  __syncthreads();
  if (tid < 128) sPq[tid] = pqs[tid] + pqs[128 + tid];
  __syncthreads();
  for (int tile = jt; tile < 19; tile += 8)
    energy_tile(b, tile, aw, awc, lcW, ldW, vw, sPq, pm, e_ws, tid);
}

// ---------------- C: softmax + ctx (8-way d-split) ----------------
__device__ __forceinline__ void soft_phase(int b, int dsl, const float* __restrict__ e_ws,
    const int* __restrict__ lens, const float* __restrict__ mem,
    float* __restrict__ aw, float* __restrict__ awc, float* __restrict__ ctx,
    float* __restrict__ out, int t, int tid){
  __shared__ float se[300];
  __shared__ float sa[300];
  __shared__ float red[256];
  int len = lens[b];
  for (int j = tid; j < 300; j += 256) se[j] = gload(&e_ws[b*300 + j]);
  __syncthreads();
  float m = -1e30f;
  for (int j = tid; j < len; j += 256) m = fmaxf(m, se[j]);
  red[tid] = m; __syncthreads();
  for (int s = 128; s > 0; s >>= 1){ if (tid < s) red[tid] = fmaxf(red[tid], red[tid + s]); __syncthreads(); }
  float mx = red[0]; __syncthreads();
  float ssum = 0.f;
  for (int j = tid; j < len; j += 256) ssum += expf(se[j] - mx);
  red[tid] = ssum; __syncthreads();
  for (int s = 128; s > 0; s >>= 1){ if (tid < s) red[tid] += red[tid + s]; __syncthreads(); }
  float inv = 1.f/red[0];
  __syncthreads();
  float* al = out + 1296000 + (size_t)b*150000 + (size_t)t*300;
  for (int j = tid; j < 300; j += 256){
    float v = (j < len) ? expf(se[j] - mx)*inv : 0.f;
    sa[j] = v;
    if (dsl == 0){
      gstore(&aw[b*300 + j], v);
      gstore(&awc[b*300 + j], gload(&awc[b*300 + j]) + v);
      al[j] = v;
    }
  }
  __syncthreads();
  int d = dsl*64 + (tid & 63), jq = tid >> 6;
  int chunk = (len + 3) >> 2;
  int j0 = jq*chunk, j1 = min(len, j0 + chunk);
  float acc = 0.f;
  const float* mb = mem + (size_t)b*153600 + d;
  for (int j = j0; j < j1; ++j) acc += sa[j]*mb[(size_t)j*512];
  red[tid] = acc; __syncthreads();
  if (jq == 0) gstore(&ctx[b*512 + d], red[tid] + red[tid+64] + red[tid+128] + red[tid+192]);
  __syncthreads();
}

// ---------------- E: mel + gate outputs ----------------
__device__ __forceinline__ void dec_out(int b, const float* __restrict__ dh, const float* __restrict__ ctx,
    const float* __restrict__ pWT, const float* __restrict__ projb,
    const float* __restrict__ gateW, const float* __restrict__ gateb,
    float* __restrict__ out, int t, int tid){
  __shared__ float sDh[1024];
  __shared__ float sCtx[512];
  __shared__ float red[256];
  __shared__ float melp[3][80];
  for (int i = tid; i < 1024; i += 256) sDh[i] = dh[b*1024 + i];    // cached (ring slot)
  for (int i = tid; i < 512; i += 256) sCtx[i] = ctx[b*512 + i];    // cached (ring slot)
  __syncthreads();
  if (tid < 240){
    int m = tid % 80, seg = tid / 80;
    float mp = 0.f;
    for (int k = seg*512; k < seg*512 + 512; ++k){
      float x = (k < 1024) ? sDh[k] : sCtx[k - 1024];
      mp += x * pWT[(size_t)k*80 + m];
    }
    melp[seg][m] = mp;
  }
  float g = 0.f;
  for (int k = tid; k < 1536; k += 256){
    float x = (k < 1024) ? sDh[k] : sCtx[k - 1024];
    g += x * gateW[k];
  }
  red[tid] = g; __syncthreads();
  for (int s = 128; s > 0; s >>= 1){ if (tid < s) red[tid] += red[tid + s]; __syncthreads(); }
  if (tid == 0) out[1280000 + (size_t)b*500 + t] = red[0] + gateb[0];
  if (tid < 80){
    float mel = melp[0][tid] + melp[1][tid] + melp[2][tid] + projb[tid];
    out[(size_t)b*40000 + (size_t)tid*500 + t] = mel;
  }
  __syncthreads();
}

// ---------------- persistent loop ----------------
struct DecParams {
  const float *memory;
  const int   *lens;
  const float *attWih, *attWhh, *attBih, *attBhh;
  const float *decWih, *decWhh, *decBih, *decBhh;
  const float *lcW, *ldW, *vw, *projb, *gateW, *gateb;
  float *ws, *out;
};

__global__ void __launch_bounds__(256, 1) k_loop(DecParams p){
  int wg = blockIdx.x, tid = threadIdx.x;
  float* ws = p.ws;
  float* decins = ws + OFF_DECINS;
  float* e_ws = ws + OFF_E;
  float* pm = ws + OFF_PM;
  float* AC = ws + OFF_AC;
  float* DC = ws + OFF_DC;
  float* aw = ws + OFF_AW;
  float* awc = ws + OFF_AWC;
  float* qWT = ws + OFF_QWT;
  float* pWT = ws + OFF_PROJWT;
  unsigned* slots = (unsigned*)(ws + OFF_SLOTS);
  unsigned* gen = slots + 4096;
  unsigned ep = 0;

#define AHR(s) (ws + OFF_AHR + (size_t)(s)*32768)
#define DHR(s) (ws + OFF_DHR + (size_t)(s)*32768)
#define CXR(s) (ws + OFF_CXR + (size_t)(s)*16384)

  // prologue: zero all ring slots at the coherence point (write-through)
  for (unsigned i = (unsigned)wg*256u + tid; i < (unsigned)RINGS_N; i += 65536u)
    gstore(ws + OFF_AHR + i, 0.f);
  gbar(slots, gen, ++ep);

  // A for t=0: ah(0) = LSTM([x_0, ctx=0], h=0) -> ah ring slot 1
  lstm_block(wg, p.attWih, p.attWhh, p.attBih, p.attBhh,
             decins, PRE, CXR(0), AHR(0), 1792, AC, AHR(1), tid);
  gbar(slots, gen, ++ep);

  for (int t = 0; t < TDEC; ++t){
    int cu = (t + 1) % RD, pr = t % RD;
    // B: pq + energy  [b = wg>>3, jt = wg&7]
    pq_energy(wg >> 3, wg & 7, AHR(cu), qWT, aw, awc, p.lcW, p.ldW, p.vw, pm, e_ws, tid);
    gbar(slots, gen, ++ep);
    // C: softmax + ctx  [b = wg>>3, dslice = wg&7]
    soft_phase(wg >> 3, wg & 7, e_ws, p.lens, p.memory, aw, awc, CXR(cu), p.out, t, tid);
    gbar(slots, gen, ++ep);
    // D: dec LSTM fused
    lstm_block(wg, p.decWih, p.decWhh, p.decBih, p.decBhh,
               AHR(cu), 1024, CXR(cu), DHR(pr), 2560, DC, DHR(cu), tid);
    gbar(slots, gen, ++ep);
    // E (32 blocks) then A(t+1) (all blocks)
    if (wg < 32)
      dec_out(wg, DHR(cu), CXR(cu), pWT, p.projb, p.gateW, p.gateb, p.out, t, tid);
    if (t + 1 < TDEC)
      lstm_block(wg, p.attWih, p.attWhh, p.attBih, p.attBhh,
                 decins + (size_t)(t + 1)*NB*PRE, PRE, CXR(cu), AHR(cu), 1792,
                 AC, AHR((t + 2) % RD), tid);
    gbar(slots, gen, ++ep);
  }
#undef AHR
#undef DHR
#undef CXR
}

// ---------------- host ----------------
extern "C" void kernel_launch(void* const* d_in, const int* in_sizes, int n_in,
                              void* d_out, int out_size, void* d_ws, size_t ws_size,
                              hipStream_t stream) {
  const float* memory   = (const float*)d_in[0];
  const float* dec_in   = (const float*)d_in[1];
  const int*   lens     = (const int*)  d_in[2];
  const float* pre_W1   = (const float*)d_in[3];
  const float* pre_W2   = (const float*)d_in[4];
  const float* att_Wih  = (const float*)d_in[5];
  const float* att_Whh  = (const float*)d_in[6];
  const float* att_bih  = (const float*)d_in[7];
  const float* att_bhh  = (const float*)d_in[8];
  const float* q_W      = (const float*)d_in[9];
  const float* m_W      = (const float*)d_in[10];
  const float* v_w      = (const float*)d_in[11];
  const float* lc_W     = (const float*)d_in[12];
  const float* ld_W     = (const float*)d_in[13];
  const float* dec_Wih  = (const float*)d_in[14];
  const float* dec_Whh  = (const float*)d_in[15];
  const float* dec_bih  = (const float*)d_in[16];
  const float* dec_bhh  = (const float*)d_in[17];
  const float* proj_W   = (const float*)d_in[18];
  const float* proj_b   = (const float*)d_in[19];
  const float* gate_W   = (const float*)d_in[20];
  const float* gate_b   = (const float*)d_in[21];
  float* out = (float*)d_out;
  float* ws  = (float*)d_ws;

  // Partitionable (foldlike) split of jax.random.key(1)
  unsigned k10, k11, k20, k21;
  tf2x32(0u, 1u, 0u, 0u, k10, k11);
  tf2x32(0u, 1u, 0u, 1u, k20, k21);

  k_setup<<<1024, 256, 0, stream>>>(ws, q_W, proj_W, m_W, pre_W1, pre_W2);
  k_prenet1<<<TDEC*NB, 256, 0, stream>>>(dec_in, ws + OFF_W1T, ws + OFF_H1M, k10, k11);
  k_prenet2<<<TDEC*NB, 256, 0, stream>>>(ws + OFF_H1M, ws + OFF_W2T, ws + OFF_DECINS, k20, k21);
  k_procmem<<<NB*TENC, 128, 0, stream>>>(memory, ws + OFF_MWT, ws + OFF_PM);

  DecParams hp;
  hp.memory = memory; hp.lens = lens;
  hp.attWih = att_Wih; hp.attWhh = att_Whh; hp.attBih = att_bih; hp.attBhh = att_bhh;
  hp.decWih = dec_Wih; hp.decWhh = dec_Whh; hp.decBih = dec_bih; hp.decBhh = dec_bhh;
  hp.lcW = lc_W; hp.ldW = ld_W; hp.vw = v_w; hp.projb = proj_b; hp.gateW = gate_W; hp.gateb = gate_b;
  hp.ws = ws; hp.out = out;
  k_loop<<<256, 256, 0, stream>>>(hp);
}